// Round 2
// baseline (5122.250 us; speedup 1.0000x reference)
//
#include <hip/hip_runtime.h>
#include <hip/hip_bf16.h>
#include <math.h>

#define B_ 8
#define C_ 256
#define S_ 64
#define H_ 128
#define W_ 128
#define HW_ (H_*W_)

// ---------------- generic direct conv3x3, pad=1 ----------------
// tile: 64 px (one row segment) x 32 out-ch, 256 threads, 4px x 2co per thread
// grid: x = (W/64)*(COUT/32), y = H, z = B
template<int CIN>
__global__ __launch_bounds__(256) void conv3x3_k(const float* __restrict__ in,
                                                 const float* __restrict__ wgt,
                                                 float* __restrict__ out, int COUT)
{
    const int KC = 16;
    __shared__ float slds[KC][3][68];    // [ci][row][px: -1..64]
    __shared__ float wlds[KC][9][33];    // [ci][tap][co] (padded)
    const int t = threadIdx.x;
    const int nCoT = COUT >> 5;
    const int pxt = blockIdx.x / nCoT;
    const int cob = (blockIdx.x % nCoT) << 5;
    const int y   = blockIdx.y;
    const int b   = blockIdx.z;
    const int px0 = pxt * 64;
    const int tpx = t & 15;     // 16 px-groups of 4
    const int tco = t >> 4;     // 16 co-groups of 2

    float acc[4][2] = {};

    for (int c0 = 0; c0 < CIN; c0 += KC) {
        for (int idx = t; idx < KC*3*66; idx += 256) {
            int px  = idx % 66;
            int row = (idx/66) % 3;
            int ci  = idx / 198;
            int gx = px0 + px - 1;
            int gy = y + row - 1;
            float v = 0.f;
            if ((unsigned)gx < W_ && (unsigned)gy < H_)
                v = in[(((size_t)b*CIN + c0+ci)*H_ + gy)*W_ + gx];
            slds[ci][row][px] = v;
        }
        for (int idx = t; idx < 32*KC*9; idx += 256) {
            int tap = idx % 9;
            int ci  = (idx/9) % KC;
            int co  = idx / (9*KC);
            wlds[ci][tap][co] = wgt[(size_t)(cob+co)*CIN*9 + (size_t)(c0+ci)*9 + tap];
        }
        __syncthreads();
        for (int ci = 0; ci < KC; ++ci) {
            #pragma unroll
            for (int ky = 0; ky < 3; ++ky) {
                float fin[6];
                #pragma unroll
                for (int j = 0; j < 6; ++j) fin[j] = slds[ci][ky][tpx*4 + j];
                #pragma unroll
                for (int kx = 0; kx < 3; ++kx) {
                    float w0 = wlds[ci][ky*3+kx][tco*2+0];
                    float w1 = wlds[ci][ky*3+kx][tco*2+1];
                    #pragma unroll
                    for (int p = 0; p < 4; ++p) {
                        acc[p][0] += fin[p+kx]*w0;
                        acc[p][1] += fin[p+kx]*w1;
                    }
                }
            }
        }
        __syncthreads();
    }
    #pragma unroll
    for (int p = 0; p < 4; ++p)
        #pragma unroll
        for (int c2 = 0; c2 < 2; ++c2) {
            int px = px0 + tpx*4 + p;
            int co = cob + tco*2 + c2;
            out[(((size_t)b*COUT + co)*H_ + y)*W_ + px] = acc[p][c2];
        }
}

// ---------------- channel LayerNorm (in-place, fp32), per-pixel over CC ----------------
template<int CC>
__global__ __launch_bounds__(256) void cln_k(float* __restrict__ io,
                                             const float* __restrict__ w,
                                             const float* __restrict__ bi)
{
    size_t g = (size_t)blockIdx.x*256 + threadIdx.x;   // pixel id over B*HW
    int b  = (int)(g / HW_);
    int hw = (int)(g % HW_);
    float* base = io + ((size_t)b*CC)*HW_ + hw;
    float s = 0.f, ss = 0.f;
    for (int c = 0; c < CC; ++c) { float v = base[(size_t)c*HW_]; s += v; ss += v*v; }
    float mu  = s * (1.0f/CC);
    float var = ss * (1.0f/CC) - mu*mu;
    float rs  = rsqrtf(var + 1e-5f);
    for (int c = 0; c < CC; ++c) {
        float v = base[(size_t)c*HW_];
        base[(size_t)c*HW_] = (v - mu)*rs*w[c] + bi[c];
    }
}

// ---------------- generic 1x1 conv (GEMM), optional 2-input concat ----------------
// tile: 128 px x 32 co, 256 threads, 4px x 4co per thread
// grid: x = HW/128, y = COUT/32, z = B
template<int C0, int C1>
__global__ __launch_bounds__(256) void conv1x1_k(const float* __restrict__ in0,
                                                 const float* __restrict__ in1,
                                                 const float* __restrict__ wgt,
                                                 float* __restrict__ out, int COUT)
{
    const int CIN = C0 + C1;
    __shared__ float xl[32][128];
    __shared__ float wl[32][33];
    const int t = threadIdx.x;
    const int p0  = blockIdx.x * 128;
    const int cob = blockIdx.y * 32;
    const int b   = blockIdx.z;
    const int tpx = t & 31;   // 32 groups x 4px
    const int tco = t >> 5;   // 8 groups x 4co
    float acc[4][4] = {};

    for (int c0 = 0; c0 < CIN; c0 += 32) {
        for (int idx = t; idx < 32*128; idx += 256) {
            int px = idx & 127, ci = idx >> 7;
            int cc = c0 + ci;
            float v;
            if (cc < C0) v = in0[((size_t)b*C0 + cc)*HW_ + p0 + px];
            else         v = in1[((size_t)b*C1 + (cc - C0))*HW_ + p0 + px];
            xl[ci][px] = v;
        }
        for (int idx = t; idx < 32*32; idx += 256) {
            int ci = idx & 31, co = idx >> 5;
            wl[ci][co] = wgt[(size_t)(cob+co)*CIN + c0 + ci];
        }
        __syncthreads();
        for (int ci = 0; ci < 32; ++ci) {
            float4 xv = *(const float4*)&xl[ci][tpx*4];
            float w0 = wl[ci][tco*4+0], w1 = wl[ci][tco*4+1];
            float w2 = wl[ci][tco*4+2], w3 = wl[ci][tco*4+3];
            acc[0][0]+=xv.x*w0; acc[0][1]+=xv.x*w1; acc[0][2]+=xv.x*w2; acc[0][3]+=xv.x*w3;
            acc[1][0]+=xv.y*w0; acc[1][1]+=xv.y*w1; acc[1][2]+=xv.y*w2; acc[1][3]+=xv.y*w3;
            acc[2][0]+=xv.z*w0; acc[2][1]+=xv.z*w1; acc[2][2]+=xv.z*w2; acc[2][3]+=xv.z*w3;
            acc[3][0]+=xv.w*w0; acc[3][1]+=xv.w*w1; acc[3][2]+=xv.w*w2; acc[3][3]+=xv.w*w3;
        }
        __syncthreads();
    }
    #pragma unroll
    for (int cc = 0; cc < 4; ++cc)
        #pragma unroll
        for (int pp = 0; pp < 4; ++pp)
            out[((size_t)b*COUT + cob + tco*4 + cc)*HW_ + p0 + tpx*4 + pp] = acc[pp][cc];
}

// ---------------- depthwise 3x3 (+optional exact GELU) ----------------
template<bool GELU>
__global__ __launch_bounds__(256) void dw3x3_k(const float* __restrict__ in,
                                               const float* __restrict__ wgt,
                                               float* __restrict__ out, int CH)
{
    size_t g = (size_t)blockIdx.x*256 + threadIdx.x;  // over B*CH*HW
    int xcol = (int)(g % W_);
    int yrow = (int)((g / W_) % H_);
    size_t bc = g / HW_;
    int ch = (int)(bc % CH);
    const float* ib = in + bc*HW_;
    float acc = 0.f;
    #pragma unroll
    for (int ky = 0; ky < 3; ++ky) {
        int gy = yrow + ky - 1;
        if ((unsigned)gy >= H_) continue;
        #pragma unroll
        for (int kx = 0; kx < 3; ++kx) {
            int gx = xcol + kx - 1;
            if ((unsigned)gx >= W_) continue;
            acc += ib[gy*W_ + gx] * wgt[ch*9 + ky*3 + kx];
        }
    }
    if (GELU) acc = 0.5f*acc*(1.f + erff(acc*0.70710678118654752f));
    out[g] = acc;
}

// ---------------- attention stats: per (b,head) -> softmax probs [8][8] ----------------
__global__ __launch_bounds__(256) void attn_k(const float* __restrict__ q,
                                              const float* __restrict__ kv,
                                              const float* __restrict__ temp,
                                              float* __restrict__ attn)
{
    int b = blockIdx.x >> 3, h = blockIdx.x & 7;
    int t = threadIdx.x;
    const float* qb = q  + ((size_t)b*S_  + h*8)*HW_;
    const float* kb = kv + ((size_t)b*128 + h*8)*HW_;
    float qs[8] = {}, ks[8] = {}, dt[8][8] = {{}};
    for (int n = t; n < HW_; n += 256) {
        float qv[8], kvv[8];
        #pragma unroll
        for (int i = 0; i < 8; ++i) { qv[i] = qb[(size_t)i*HW_ + n]; kvv[i] = kb[(size_t)i*HW_ + n]; }
        #pragma unroll
        for (int i = 0; i < 8; ++i) { qs[i] += qv[i]*qv[i]; ks[i] += kvv[i]*kvv[i]; }
        #pragma unroll
        for (int i = 0; i < 8; ++i)
            #pragma unroll
            for (int j = 0; j < 8; ++j) dt[i][j] += qv[i]*kvv[j];
    }
    __shared__ float red[4][80];
    __shared__ float fin[80];
    int lane = t & 63, wv = t >> 6;
    #pragma unroll
    for (int i = 0; i < 8; ++i) { float v = qs[i]; for (int m=1;m<64;m<<=1) v += __shfl_xor(v,m); if (!lane) red[wv][i] = v; }
    #pragma unroll
    for (int i = 0; i < 8; ++i) { float v = ks[i]; for (int m=1;m<64;m<<=1) v += __shfl_xor(v,m); if (!lane) red[wv][8+i] = v; }
    #pragma unroll
    for (int i = 0; i < 8; ++i)
        #pragma unroll
        for (int j = 0; j < 8; ++j) { float v = dt[i][j]; for (int m=1;m<64;m<<=1) v += __shfl_xor(v,m); if (!lane) red[wv][16+i*8+j] = v; }
    __syncthreads();
    if (t < 80) fin[t] = red[0][t] + red[1][t] + red[2][t] + red[3][t];
    __syncthreads();
    if (t < 8) {
        int i = t;
        float qn = fmaxf(sqrtf(fin[i]), 1e-12f);
        float tm = temp[h];
        float l[8]; float mx = -1e30f;
        #pragma unroll
        for (int j = 0; j < 8; ++j) {
            float kn = fmaxf(sqrtf(fin[8+j]), 1e-12f);
            l[j] = fin[16+i*8+j] / (qn*kn) * tm;
            mx = fmaxf(mx, l[j]);
        }
        float se = 0.f;
        #pragma unroll
        for (int j = 0; j < 8; ++j) { l[j] = expf(l[j]-mx); se += l[j]; }
        float inv = 1.f/se;
        #pragma unroll
        for (int j = 0; j < 8; ++j) attn[(((size_t)b*8 + h)*8 + i)*8 + j] = l[j]*inv;
    }
}

// ---------------- fused (attn @ v) + project_out : po = (w_po*blockdiag(attn)) @ v ----------------
// grid: x = HW/512, z = B; 256 threads, 2 px per thread
__global__ __launch_bounds__(256) void po_k(const float* __restrict__ attn,
                                            const float* __restrict__ wpo,
                                            const float* __restrict__ kv,
                                            float* __restrict__ out)
{
    __shared__ float M[64][64];
    int b = blockIdx.z, t = threadIdx.x;
    for (int idx = t; idx < 4096; idx += 256) {
        int co = idx >> 6, d = idx & 63, h = d >> 3, j = d & 7;
        float s = 0.f;
        #pragma unroll
        for (int i = 0; i < 8; ++i)
            s += wpo[co*64 + h*8 + i] * attn[(((size_t)b*8 + h)*8 + i)*8 + j];
        M[co][d] = s;
    }
    __syncthreads();
    int n0 = blockIdx.x*512 + t;
    const float* vb = kv + ((size_t)b*128 + 64)*HW_;
    float a0[64] = {}, a1[64] = {};
    for (int d = 0; d < 64; ++d) {
        float v0 = vb[(size_t)d*HW_ + n0];
        float v1 = vb[(size_t)d*HW_ + n0 + 256];
        #pragma unroll
        for (int co = 0; co < 64; ++co) { float m = M[co][d]; a0[co] += m*v0; a1[co] += m*v1; }
    }
    float* ob = out + (size_t)b*S_*HW_;
    #pragma unroll
    for (int co = 0; co < 64; ++co) {
        ob[(size_t)co*HW_ + n0]       = a0[co];
        ob[(size_t)co*HW_ + n0 + 256] = a1[co];
    }
}

extern "C" void kernel_launch(void* const* d_in, const int* in_sizes, int n_in,
                              void* d_out, int out_size, void* d_ws, size_t ws_size,
                              hipStream_t stream) {
    (void)in_sizes; (void)n_in; (void)out_size; (void)ws_size;
    const float* x        = (const float*)d_in[0];
    const float* y        = (const float*)d_in[1];
    const float* w_cq     = (const float*)d_in[2];
    const float* w_ckv    = (const float*)d_in[3];
    const float* ln_q_w   = (const float*)d_in[4];
    const float* ln_q_b   = (const float*)d_in[5];
    const float* ln_kv_w  = (const float*)d_in[6];
    const float* ln_kv_b  = (const float*)d_in[7];
    const float* w_kv     = (const float*)d_in[8];
    const float* w_kvdw   = (const float*)d_in[9];
    const float* w_q      = (const float*)d_in[10];
    const float* temperature = (const float*)d_in[11];
    const float* w_po     = (const float*)d_in[12];
    const float* w_expand = (const float*)d_in[13];
    const float* ln_out_w = (const float*)d_in[14];
    const float* ln_out_b = (const float*)d_in[15];
    const float* w_ffn1   = (const float*)d_in[16];
    const float* w_ffn_dw = (const float*)d_in[17];
    const float* w_ffn2   = (const float*)d_in[18];
    float* outp = (float*)d_out;

    // fp32 workspace layout, SZS = B*S*HW = 8,388,608 floats (33.5 MB).
    // Peak ws extent = 4*SZS = 128 MiB; po/f1 staged in d_out (dead before final write).
    float* fws = (float*)d_ws;
    const size_t SZS = (size_t)B_*S_*HW_;
    float* t_ykv  = fws;               // [0,S)      live 1-3
    float* t_kv1  = fws + 2*SZS;       // [2S,4S)    live 3-4
    float* t_kvd  = fws;               // [0,2S)     live 4-9 (ykv dead)
    float* t_xq   = fws + 2*SZS;       // [2S,3S)    live 5-7 (kv1 dead)
    float* t_q    = fws + 3*SZS;       // [3S,4S)    live 7-8
    float* t_attn = fws + 2*SZS;       // 4096 f     live 8-9 (xq dead)
    float* t_po   = outp;              // d_out[0,S) live 9-10
    float* t_vexp = fws;               // [0,4S)     live 10-12 (kvd/q/attn dead)
    float* t_f1   = outp;              // d_out 4S   live 12-13 (po dead)
    float* t_f2   = fws;               // [0,4S)     live 13-14 (vexp dead)

    // 1-2: ykv = CLN(conv3x3(y, w_ckv))  256->64
    conv3x3_k<256><<<dim3(4,128,8), 256, 0, stream>>>(y, w_ckv, t_ykv, 64);
    cln_k<64><<<512, 256, 0, stream>>>(t_ykv, ln_kv_w, ln_kv_b);
    // 3: kv1 = conv1x1(ykv, w_kv)  64->128
    conv1x1_k<64, 0><<<dim3(128,4,8), 256, 0, stream>>>(t_ykv, (const float*)nullptr, w_kv, t_kv1, 128);
    // 4: kvd = depthwise3x3(kv1)
    dw3x3_k<false><<<65536, 256, 0, stream>>>(t_kv1, w_kvdw, t_kvd, 128);
    // 5-6: xq = CLN(conv3x3(x, w_cq))  256->64
    conv3x3_k<256><<<dim3(4,128,8), 256, 0, stream>>>(x, w_cq, t_xq, 64);
    cln_k<64><<<512, 256, 0, stream>>>(t_xq, ln_q_w, ln_q_b);
    // 7: q = conv3x3(xq, w_q)  64->64
    conv3x3_k<64><<<dim3(4,128,8), 256, 0, stream>>>(t_xq, w_q, t_q, 64);
    // 8: attention probs
    attn_k<<<64, 256, 0, stream>>>(t_q, t_kvd, temperature, t_attn);
    // 9: po = (w_po . blockdiag(attn)) @ v
    po_k<<<dim3(32,1,8), 256, 0, stream>>>(t_attn, w_po, t_kvd, t_po);
    // 10-11: vn = CLN(conv3x3(po, w_expand))  64->256
    conv3x3_k<64><<<dim3(16,128,8), 256, 0, stream>>>(t_po, w_expand, t_vexp, 256);
    cln_k<256><<<512, 256, 0, stream>>>(t_vexp, ln_out_w, ln_out_b);
    // 12: f1 = conv1x1(cat(x, vn), w_ffn1)  512->256
    conv1x1_k<256, 256><<<dim3(128,8,8), 256, 0, stream>>>(x, t_vexp, w_ffn1, t_f1, 256);
    // 13: f2 = gelu(depthwise3x3(f1))
    dw3x3_k<true><<<131072, 256, 0, stream>>>(t_f1, w_ffn_dw, t_f2, 256);
    // 14: out = conv1x1(f2, w_ffn2)  256->256
    conv1x1_k<256, 0><<<dim3(128,8,8), 256, 0, stream>>>(t_f2, (const float*)nullptr, w_ffn2, outp, 256);
}

// Round 3
// 1627.292 us; speedup vs baseline: 3.1477x; 3.1477x over previous
//
#include <hip/hip_runtime.h>
#include <hip/hip_bf16.h>
#include <math.h>

#define B_ 8
#define C_ 256
#define S_ 64
#define H_ 128
#define W_ 128
#define HW_ (H_*W_)
#define P_ (B_*HW_)

typedef __attribute__((ext_vector_type(8))) short short8;
typedef __attribute__((ext_vector_type(4))) float f32x4;

__device__ __forceinline__ float b2f(unsigned short u){ return __uint_as_float(((unsigned)u)<<16); }
__device__ __forceinline__ unsigned short f2b(float f){
    __hip_bfloat16 h = __float2bfloat16(f);
    return *reinterpret_cast<unsigned short*>(&h);
}
__device__ __forceinline__ void up8(uint4 u, float* f){
    unsigned v0=u.x,v1=u.y,v2=u.z,v3=u.w;
    f[0]=__uint_as_float(v0<<16); f[1]=__uint_as_float(v0&0xffff0000u);
    f[2]=__uint_as_float(v1<<16); f[3]=__uint_as_float(v1&0xffff0000u);
    f[4]=__uint_as_float(v2<<16); f[5]=__uint_as_float(v2&0xffff0000u);
    f[6]=__uint_as_float(v3<<16); f[7]=__uint_as_float(v3&0xffff0000u);
}
__device__ __forceinline__ uint4 pk8(const float* f){
    uint4 u;
    u.x = (unsigned)f2b(f[0]) | ((unsigned)f2b(f[1])<<16);
    u.y = (unsigned)f2b(f[2]) | ((unsigned)f2b(f[3])<<16);
    u.z = (unsigned)f2b(f[4]) | ((unsigned)f2b(f[5])<<16);
    u.w = (unsigned)f2b(f[6]) | ((unsigned)f2b(f[7])<<16);
    return u;
}

// ---------------- NCHW fp32 -> NHWC bf16 pack (tile transpose) ----------------
// grid (HW/64, C/64, B), 256 thr
__global__ __launch_bounds__(256) void pack_k(const float* __restrict__ in,
                                              unsigned short* __restrict__ out)
{
    __shared__ unsigned short tl[64][72];
    const int t = threadIdx.x;
    const int p0 = blockIdx.x*64, c0 = blockIdx.y*64, b = blockIdx.z;
    const float* ib = in + ((size_t)b*C_ + c0)*HW_ + p0;
    for (int i = t; i < 1024; i += 256){
        int ci = i >> 4, px = (i & 15)*4;
        float4 v = *(const float4*)(ib + (size_t)ci*HW_ + px);
        tl[px+0][ci]=f2b(v.x); tl[px+1][ci]=f2b(v.y); tl[px+2][ci]=f2b(v.z); tl[px+3][ci]=f2b(v.w);
    }
    __syncthreads();
    unsigned short* ob = out + ((size_t)b*HW_ + p0)*C_ + c0;
    for (int i = t; i < 512; i += 256){
        int px = i >> 3, c8 = (i & 7)*8;
        *(uint4*)(ob + (size_t)px*C_ + c8) = *(uint4*)&tl[px][c8];
    }
}

// ---------------- prepack all static weights -> [tap][co][ci] bf16 ----------------
// grid 2096 x 256 (= 536576 elements exactly)
__global__ __launch_bounds__(256) void prep_k(const float* __restrict__ cq, const float* __restrict__ ckv,
                                              const float* __restrict__ q,  const float* __restrict__ kv,
                                              const float* __restrict__ f1, const float* __restrict__ f2,
                                              unsigned short* o_cq, unsigned short* o_ckv, unsigned short* o_q,
                                              unsigned short* o_kv, unsigned short* o_f1, unsigned short* o_f2)
{
    int i = blockIdx.x*256 + threadIdx.x;
    if (i < 147456) {                       // cq: CO=64 CI=256 KS=3
        int tap = i/16384, rem = i%16384, co = rem>>8, ci = rem&255;
        o_cq[i] = f2b(cq[(size_t)(co*256+ci)*9 + tap]);
    } else if (i < 294912) {                // ckv
        int e = i-147456;
        int tap = e/16384, rem = e%16384, co = rem>>8, ci = rem&255;
        o_ckv[e] = f2b(ckv[(size_t)(co*256+ci)*9 + tap]);
    } else if (i < 331776) {                // q: 64x64x3x3
        int e = i-294912;
        int tap = e/4096, rem = e%4096, co = rem>>6, ci = rem&63;
        o_q[e] = f2b(q[(size_t)(co*64+ci)*9 + tap]);
    } else if (i < 339968) {                // kv 1x1: 128x64
        int e = i-331776; o_kv[e] = f2b(kv[e]);
    } else if (i < 471040) {                // ffn1 1x1: 256x512
        int e = i-339968; o_f1[e] = f2b(f1[e]);
    } else {                                // ffn2 1x1: 256x256
        int e = i-471040; o_f2[e] = f2b(f2[e]);
    }
}

// ---------------- unified MFMA conv (KS=3 pad1 or KS=1), NHWC bf16 ----------------
// BM=128 px; block 256 thr = 4 waves (WM x WN); BN co per block.
// A staged in LDS as [kgrp4][row][px][8ci]; B read from prepacked [tap][COUT][CINT] global.
// OUTM 0: bf16 NHWC (stride so). OUTM 1: fp32 NCHW (KS=1 only).
template<int C0, int C1, int COUT, int KS, int WM, int WN, int BN, int OUTM>
__global__ __launch_bounds__(256) void mconv_k(const unsigned short* __restrict__ in0, int s0,
                                               const unsigned short* __restrict__ in1, int s1,
                                               const unsigned short* __restrict__ wp, long wpbs,
                                               void* __restrict__ outp, int so)
{
    constexpr int CINT = C0 + C1;
    constexpr int KB   = CINT / 32;
    constexpr int MT   = 128 / (16*WM);
    constexpr int NT   = BN / (16*WN);
    constexpr int RWS  = (KS==3) ? 4 : 1;
    constexpr int PXS  = (KS==3) ? 66 : 128;
    constexpr int NTR  = RWS*PXS*4;
    constexpr int ASZ  = 4*RWS*PXS*8;
    constexpr int ESZ  = (OUTM==0) ? 128*BN : 0;
    __shared__ alignas(16) unsigned short sbuf[(ASZ > ESZ) ? ASZ : ESZ];

    const int t = threadIdx.x;
    const int b = blockIdx.z;
    const int cob = blockIdx.y * BN;
    const size_t pb = (size_t)b * HW_;
    int y0 = 0, x0 = 0; size_t p0 = 0;
    if (KS==3) { y0 = (blockIdx.x >> 1) * 2; x0 = (blockIdx.x & 1) * 64; }
    else       { p0 = (size_t)blockIdx.x * 128; }

    const int l = t & 63, w = t >> 6;
    const int wy = w / WN, wx = w % WN;
    const int lrow = l & 15, lk = l >> 4;
    const unsigned short* wpb = wp + (size_t)b * wpbs;

    f32x4 acc[MT][NT] = {};

    for (int kb = 0; kb < KB; ++kb) {
        const int cg = kb*32;
        for (int i = t; i < NTR; i += 256) {
            int g = i & 3, pr = i >> 2;
            int px = pr % PXS, row = pr / PXS;
            uint4 v = {0,0,0,0};
            if (KS==3) {
                int gy = y0 + row - 1, gx = x0 + px - 1;
                if ((unsigned)gy < (unsigned)H_ && (unsigned)gx < (unsigned)W_) {
                    size_t p = (size_t)gy*W_ + gx;
                    int c = cg + g*8;
                    const unsigned short* sp = (c < C0) ? in0 + (pb+p)*s0 + c
                                                        : in1 + (pb+p)*s1 + (c - C0);
                    v = *(const uint4*)sp;
                }
            } else {
                size_t p = p0 + px;
                int c = cg + g*8;
                const unsigned short* sp = (c < C0) ? in0 + (pb+p)*s0 + c
                                                    : in1 + (pb+p)*s1 + (c - C0);
                v = *(const uint4*)sp;
            }
            *(uint4*)&sbuf[((g*RWS + row)*PXS + px)*8] = v;
        }
        __syncthreads();
        #pragma unroll
        for (int tap = 0; tap < KS*KS; ++tap) {
            const int ky = tap/KS, kx = tap%KS;
            short8 bf[NT];
            #pragma unroll
            for (int n = 0; n < NT; ++n) {
                int co = cob + wx*(16*NT) + n*16 + lrow;
                bf[n] = *(const short8*)(wpb + ((size_t)(tap*COUT + co))*CINT + cg + lk*8);
            }
            short8 af[MT];
            #pragma unroll
            for (int m = 0; m < MT; ++m) {
                int pl = wy*(16*MT) + m*16 + lrow;
                int addr;
                if (KS==3) {
                    int r = (pl>>6) + ky, xx = (pl&63) + kx;
                    addr = ((lk*RWS + r)*PXS + xx)*8;
                } else {
                    addr = (lk*RWS*PXS + pl)*8;
                }
                af[m] = *(const short8*)&sbuf[addr];
            }
            #pragma unroll
            for (int m = 0; m < MT; ++m)
                #pragma unroll
                for (int n = 0; n < NT; ++n)
                    acc[m][n] = __builtin_amdgcn_mfma_f32_16x16x32_bf16(af[m], bf[n], acc[m][n], 0, 0, 0);
        }
        __syncthreads();
    }

    if (OUTM == 0) {
        unsigned short* out = (unsigned short*)outp;
        #pragma unroll
        for (int m = 0; m < MT; ++m)
            #pragma unroll
            for (int n = 0; n < NT; ++n) {
                int co = wx*(16*NT) + n*16 + lrow;
                #pragma unroll
                for (int r = 0; r < 4; ++r) {
                    int pl = wy*(16*MT) + m*16 + lk*4 + r;
                    sbuf[pl*BN + co] = f2b(acc[m][n][r]);
                }
            }
        __syncthreads();
        for (int i = t; i < 128*BN/8; i += 256) {
            int pl = i / (BN/8), c8 = (i % (BN/8))*8;
            size_t p = (KS==3) ? ((size_t)(y0 + (pl>>6))*W_ + (size_t)(x0 + (pl&63))) : (p0 + pl);
            *(uint4*)(out + (pb + p)*so + cob + c8) = *(uint4*)&sbuf[pl*BN + c8];
        }
    } else {
        float* out = (float*)outp;
        #pragma unroll
        for (int m = 0; m < MT; ++m)
            #pragma unroll
            for (int n = 0; n < NT; ++n) {
                int co = cob + wx*(16*NT) + n*16 + lrow;
                size_t p = p0 + (size_t)(wy*(16*MT) + m*16 + lk*4);
                *(f32x4*)(out + ((size_t)(b*COUT + co))*HW_ + p) = acc[m][n];
            }
    }
}

// ---------------- channel LayerNorm over C (NHWC bf16, in place) ----------------
template<int C>
__global__ __launch_bounds__(256) void cln_k(unsigned short* __restrict__ io,
                                             const float* __restrict__ wg,
                                             const float* __restrict__ bi)
{
    size_t pix = (size_t)blockIdx.x*256 + threadIdx.x;
    unsigned short* row = io + pix*C;
    uint4 raw[C/8];
    float s = 0.f, ss = 0.f;
    #pragma unroll
    for (int i = 0; i < C/8; ++i) {
        raw[i] = *(const uint4*)(row + i*8);
        float f[8]; up8(raw[i], f);
        #pragma unroll
        for (int j = 0; j < 8; ++j) { s += f[j]; ss += f[j]*f[j]; }
    }
    float mu = s*(1.f/C);
    float rs = rsqrtf(ss*(1.f/C) - mu*mu + 1e-5f);
    #pragma unroll
    for (int i = 0; i < C/8; ++i) {
        float f[8]; up8(raw[i], f);
        float o[8];
        #pragma unroll
        for (int j = 0; j < 8; ++j) o[j] = (f[j]-mu)*rs*wg[i*8+j] + bi[i*8+j];
        *(uint4*)(row + i*8) = pk8(o);
    }
}

// ---------------- depthwise 3x3 NHWC bf16 (+GELU) ----------------
template<int CH, bool GELU>
__global__ __launch_bounds__(256) void dw_k(const unsigned short* __restrict__ in,
                                            const float* __restrict__ wgt,
                                            unsigned short* __restrict__ out)
{
    size_t idx = (size_t)blockIdx.x*256 + threadIdx.x;   // over P_*(CH/8)
    int c8 = (int)(idx % (CH/8));
    size_t pix = idx / (CH/8);
    int p = (int)(pix % HW_);
    size_t pb = pix - p;
    int yy = p >> 7, xx = p & 127;
    float a[8] = {0,0,0,0,0,0,0,0};
    #pragma unroll
    for (int ky = 0; ky < 3; ++ky) {
        int gy = yy + ky - 1;
        if ((unsigned)gy >= (unsigned)H_) continue;
        #pragma unroll
        for (int kx = 0; kx < 3; ++kx) {
            int gx = xx + kx - 1;
            if ((unsigned)gx >= (unsigned)W_) continue;
            uint4 r = *(const uint4*)(in + (pb + (size_t)gy*W_ + gx)*CH + c8*8);
            float f[8]; up8(r, f);
            #pragma unroll
            for (int j = 0; j < 8; ++j) a[j] += f[j]*wgt[(c8*8+j)*9 + ky*3 + kx];
        }
    }
    if (GELU) {
        #pragma unroll
        for (int j = 0; j < 8; ++j) a[j] = 0.5f*a[j]*(1.f + erff(a[j]*0.70710678118654752f));
    }
    *(uint4*)(out + pix*CH + c8*8) = pk8(a);
}

// ---------------- attention probs per (b,h) ----------------
__global__ __launch_bounds__(256) void attn_k(const unsigned short* __restrict__ qc,
                                              const unsigned short* __restrict__ kvd,
                                              const float* __restrict__ temp,
                                              float* __restrict__ probs)
{
    int b = blockIdx.x >> 3, h = blockIdx.x & 7;
    int t = threadIdx.x;
    const unsigned short* qb = qc  + (size_t)b*HW_*64  + h*8;
    const unsigned short* kb = kvd + (size_t)b*HW_*128 + h*8;
    float qs[8] = {}, ks[8] = {}, dt[8][8] = {{}};
    for (int p = t; p < HW_; p += 256) {
        float qv[8], kv[8];
        up8(*(const uint4*)(qb + (size_t)p*64),  qv);
        up8(*(const uint4*)(kb + (size_t)p*128), kv);
        #pragma unroll
        for (int i = 0; i < 8; ++i) { qs[i] += qv[i]*qv[i]; ks[i] += kv[i]*kv[i]; }
        #pragma unroll
        for (int i = 0; i < 8; ++i)
            #pragma unroll
            for (int j = 0; j < 8; ++j) dt[i][j] += qv[i]*kv[j];
    }
    __shared__ float red[4][80];
    __shared__ float fin[80];
    int lane = t & 63, wv = t >> 6;
    #pragma unroll
    for (int i = 0; i < 8; ++i) { float v = qs[i]; for (int m=1;m<64;m<<=1) v += __shfl_xor(v,m); if (!lane) red[wv][i] = v; }
    #pragma unroll
    for (int i = 0; i < 8; ++i) { float v = ks[i]; for (int m=1;m<64;m<<=1) v += __shfl_xor(v,m); if (!lane) red[wv][8+i] = v; }
    #pragma unroll
    for (int i = 0; i < 8; ++i)
        #pragma unroll
        for (int j = 0; j < 8; ++j) { float v = dt[i][j]; for (int m=1;m<64;m<<=1) v += __shfl_xor(v,m); if (!lane) red[wv][16+i*8+j] = v; }
    __syncthreads();
    if (t < 80) fin[t] = red[0][t] + red[1][t] + red[2][t] + red[3][t];
    __syncthreads();
    if (t < 8) {
        int i = t;
        float qn = fmaxf(sqrtf(fin[i]), 1e-12f);
        float tm = temp[h];
        float lg[8]; float mx = -1e30f;
        #pragma unroll
        for (int j = 0; j < 8; ++j) {
            float kn = fmaxf(sqrtf(fin[8+j]), 1e-12f);
            lg[j] = fin[16+i*8+j] / (qn*kn) * tm;
            mx = fmaxf(mx, lg[j]);
        }
        float se = 0.f;
        #pragma unroll
        for (int j = 0; j < 8; ++j) { lg[j] = expf(lg[j]-mx); se += lg[j]; }
        float inv = 1.f/se;
        #pragma unroll
        for (int j = 0; j < 8; ++j) probs[(((size_t)b*8 + h)*8 + i)*8 + j] = lg[j]*inv;
    }
}

// ---------------- Mb = w_po . blockdiag(attn)  [8][64][64] ----------------
__global__ __launch_bounds__(256) void mb_k(const float* __restrict__ probs,
                                            const float* __restrict__ wpo,
                                            float* __restrict__ Mb)
{
    int b = blockIdx.x;
    for (int o = threadIdx.x; o < 4096; o += 256) {
        int co = o >> 6, d = o & 63, h = d >> 3, j = d & 7;
        float s = 0.f;
        #pragma unroll
        for (int i2 = 0; i2 < 8; ++i2)
            s += wpo[co*64 + h*8 + i2] * probs[(((size_t)b*8 + h)*8 + i2)*8 + j];
        Mb[(size_t)b*4096 + o] = s;
    }
}

// ---------------- weff[b][tap][eo][d] = sum_c w_expand[eo][c][tap] * Mb[b][c][d] ----------------
__global__ __launch_bounds__(256) void weff_k(const float* __restrict__ Mb,
                                              const float* __restrict__ wex,
                                              unsigned short* __restrict__ weff)
{
    int b = blockIdx.x / 576;
    int i = (blockIdx.x % 576)*256 + threadIdx.x;   // < 147456
    int tap = i / 16384, rem = i % 16384;
    int eo = rem >> 6, d = rem & 63;
    const float* mb = Mb + (size_t)b*4096;
    float s = 0.f;
    #pragma unroll 8
    for (int c = 0; c < 64; ++c)
        s += wex[(size_t)(eo*64 + c)*9 + tap] * mb[c*64 + d];
    weff[(size_t)b*147456 + i] = f2b(s);
}

extern "C" void kernel_launch(void* const* d_in, const int* in_sizes, int n_in,
                              void* d_out, int out_size, void* d_ws, size_t ws_size,
                              hipStream_t stream) {
    (void)in_sizes; (void)n_in; (void)out_size; (void)ws_size;
    const float* x        = (const float*)d_in[0];
    const float* y        = (const float*)d_in[1];
    const float* w_cq     = (const float*)d_in[2];
    const float* w_ckv    = (const float*)d_in[3];
    const float* ln_q_w   = (const float*)d_in[4];
    const float* ln_q_b   = (const float*)d_in[5];
    const float* ln_kv_w  = (const float*)d_in[6];
    const float* ln_kv_b  = (const float*)d_in[7];
    const float* w_kv     = (const float*)d_in[8];
    const float* w_kvdw   = (const float*)d_in[9];
    const float* w_q      = (const float*)d_in[10];
    const float* temperature = (const float*)d_in[11];
    const float* w_po     = (const float*)d_in[12];
    const float* w_expand = (const float*)d_in[13];
    const float* ln_out_w = (const float*)d_in[14];
    const float* ln_out_b = (const float*)d_in[15];
    const float* w_ffn1   = (const float*)d_in[16];
    const float* w_ffn_dw = (const float*)d_in[17];
    const float* w_ffn2   = (const float*)d_in[18];
    float* outp = (float*)d_out;

    // ---- buffer map (bytes). ws peak use ~118.1 MiB (<= 128 MiB known-safe). ----
    const size_t MB = 1u<<20;
    char* ws8 = (char*)d_ws;
    unsigned short* ykv  = (unsigned short*)(ws8 + 0);        // 16MB, live: ckv..kv1
    unsigned short* kv1  = (unsigned short*)(ws8 + 16*MB);    // 32MB, live: kv1..dw
    unsigned short* kvd  = (unsigned short*)(ws8 + 80*MB);    // 32MB, live: dw..expand
    unsigned short* xq   = (unsigned short*)(ws8 + 0);        // 16MB, live: cq..qconv
    unsigned short* qc   = (unsigned short*)(ws8 + 16*MB);    // 16MB, live: qconv..attn
    unsigned short* vexp = (unsigned short*)(ws8 + 0);        // 64MB, live: expand..ffn1
    unsigned short* f2b_ = (unsigned short*)(ws8 + 0);        // 64MB, live: dw2..ffn2
    float* probs = (float*)(ws8 + 112*MB);                    // 16KB
    float* Mb    = (float*)(ws8 + 113*MB);                    // 128KB
    unsigned short* weff = (unsigned short*)(ws8 + 114*MB);   // 2.25MB
    unsigned short* wpB  = (unsigned short*)(ws8 + 117*MB);   // 1.05MB static prepacked
    unsigned short* wp_cq  = wpB;
    unsigned short* wp_ckv = wpB + 147456;
    unsigned short* wp_q   = wpB + 294912;
    unsigned short* wp_kv  = wpB + 331776;
    unsigned short* wp_f1  = wpB + 339968;
    unsigned short* wp_f2  = wpB + 471040;
    // d_out as scratch: xb [0,64MB), yb/f1 [64,128MB)
    unsigned short* xb = (unsigned short*)d_out;
    unsigned short* yb = (unsigned short*)d_out + 32*MB;      // elements (64MB offset)
    unsigned short* f1 = yb;

    const unsigned short* NUL = (const unsigned short*)nullptr;

    // 0. prepack static weights + pack y
    prep_k<<<2096, 256, 0, stream>>>(w_cq, w_ckv, w_q, w_kv, w_ffn1, w_ffn2,
                                     wp_cq, wp_ckv, wp_q, wp_kv, wp_f1, wp_f2);
    pack_k<<<dim3(256,4,8), 256, 0, stream>>>(y, yb);
    // 1. ykv = LN(conv3x3(yb, ckv))
    mconv_k<256,0,64,3,4,1,64,0><<<dim3(128,1,8), 256, 0, stream>>>(yb,256, NUL,0, wp_ckv,0, ykv,64);
    cln_k<64><<<512, 256, 0, stream>>>(ykv, ln_kv_w, ln_kv_b);
    // 2. kv1 = conv1x1(ykv); kvd = dw3x3(kv1)
    mconv_k<64,0,128,1,2,2,128,0><<<dim3(128,1,8), 256, 0, stream>>>(ykv,64, NUL,0, wp_kv,0, kv1,128);
    dw_k<128,false><<<8192, 256, 0, stream>>>(kv1, w_kvdw, kvd);
    // 3. pack x; xq = LN(conv3x3(xb, cq)); qc = conv3x3(xq, q)
    pack_k<<<dim3(256,4,8), 256, 0, stream>>>(x, xb);
    mconv_k<256,0,64,3,4,1,64,0><<<dim3(128,1,8), 256, 0, stream>>>(xb,256, NUL,0, wp_cq,0, xq,64);
    cln_k<64><<<512, 256, 0, stream>>>(xq, ln_q_w, ln_q_b);
    mconv_k<64,0,64,3,4,1,64,0><<<dim3(128,1,8), 256, 0, stream>>>(xq,64, NUL,0, wp_q,0, qc,64);
    // 4. attention -> probs -> Mb -> per-batch effective expand weights
    attn_k<<<64, 256, 0, stream>>>(qc, kvd, temperature, probs);
    mb_k<<<8, 256, 0, stream>>>(probs, w_po, Mb);
    weff_k<<<4608, 256, 0, stream>>>(Mb, w_expand, weff);
    // 5. vexp = LN(conv3x3(v, weff_b))   (fused attn@v + project_out + expand)
    mconv_k<64,0,256,3,2,2,128,0><<<dim3(128,2,8), 256, 0, stream>>>(kvd+64,128, NUL,0, weff,147456, vexp,256);
    cln_k<256><<<512, 256, 0, stream>>>(vexp, ln_out_w, ln_out_b);
    // 6. f1 = conv1x1([xb, vn], ffn1); f2 = gelu(dw3x3(f1)); out = conv1x1(f2, ffn2) fp32 NCHW
    mconv_k<256,256,256,1,2,2,128,0><<<dim3(128,2,8), 256, 0, stream>>>(xb,256, vexp,256, wp_f1,0, f1,256);
    dw_k<256,true><<<16384, 256, 0, stream>>>(f1, w_ffn_dw, f2b_);
    mconv_k<256,0,256,1,2,2,128,1><<<dim3(128,2,8), 256, 0, stream>>>(f2b_,256, NUL,0, wp_f2,0, outp,0);
}

// Round 4
// 890.309 us; speedup vs baseline: 5.7533x; 1.8278x over previous
//
#include <hip/hip_runtime.h>
#include <hip/hip_bf16.h>
#include <math.h>

#define B_ 8
#define C_ 256
#define S_ 64
#define H_ 128
#define W_ 128
#define HW_ (H_*W_)
#define P_ (B_*HW_)

typedef __attribute__((ext_vector_type(8))) short short8;
typedef __attribute__((ext_vector_type(4))) float f32x4;

__device__ __forceinline__ float b2f(unsigned short u){ return __uint_as_float(((unsigned)u)<<16); }
__device__ __forceinline__ unsigned short f2b(float f){
    __hip_bfloat16 h = __float2bfloat16(f);
    return *reinterpret_cast<unsigned short*>(&h);
}
__device__ __forceinline__ void up8(uint4 u, float* f){
    unsigned v0=u.x,v1=u.y,v2=u.z,v3=u.w;
    f[0]=__uint_as_float(v0<<16); f[1]=__uint_as_float(v0&0xffff0000u);
    f[2]=__uint_as_float(v1<<16); f[3]=__uint_as_float(v1&0xffff0000u);
    f[4]=__uint_as_float(v2<<16); f[5]=__uint_as_float(v2&0xffff0000u);
    f[6]=__uint_as_float(v3<<16); f[7]=__uint_as_float(v3&0xffff0000u);
}
__device__ __forceinline__ uint4 pk8(const float* f){
    uint4 u;
    u.x = (unsigned)f2b(f[0]) | ((unsigned)f2b(f[1])<<16);
    u.y = (unsigned)f2b(f[2]) | ((unsigned)f2b(f[3])<<16);
    u.z = (unsigned)f2b(f[4]) | ((unsigned)f2b(f[5])<<16);
    u.w = (unsigned)f2b(f[6]) | ((unsigned)f2b(f[7])<<16);
    return u;
}

// ---------------- NCHW fp32 -> NHWC bf16 pack (tile transpose) ----------------
// grid (HW/64, C/64, B), 256 thr
__global__ __launch_bounds__(256) void pack_k(const float* __restrict__ in,
                                              unsigned short* __restrict__ out)
{
    __shared__ unsigned short tl[64][72];
    const int t = threadIdx.x;
    const int p0 = blockIdx.x*64, c0 = blockIdx.y*64, b = blockIdx.z;
    const float* ib = in + ((size_t)b*C_ + c0)*HW_ + p0;
    for (int i = t; i < 1024; i += 256){
        int ci = i >> 4, px = (i & 15)*4;
        float4 v = *(const float4*)(ib + (size_t)ci*HW_ + px);
        tl[px+0][ci]=f2b(v.x); tl[px+1][ci]=f2b(v.y); tl[px+2][ci]=f2b(v.z); tl[px+3][ci]=f2b(v.w);
    }
    __syncthreads();
    unsigned short* ob = out + ((size_t)b*HW_ + p0)*C_ + c0;
    for (int i = t; i < 512; i += 256){
        int px = i >> 3, c8 = (i & 7)*8;
        *(uint4*)(ob + (size_t)px*C_ + c8) = *(uint4*)&tl[px][c8];
    }
}

// ---------------- prepack all static weights ----------------
// GEMM weights -> [tap][co][ci] bf16 ; dw weights -> [tap][ch] bf16
// total elements = 536576 + 1152 + 2304 = 540032 ; grid 2110 x 256
__global__ __launch_bounds__(256) void prep_k(const float* __restrict__ cq, const float* __restrict__ ckv,
                                              const float* __restrict__ q,  const float* __restrict__ kv,
                                              const float* __restrict__ f1, const float* __restrict__ f2,
                                              const float* __restrict__ dwk, const float* __restrict__ dwf,
                                              unsigned short* o_cq, unsigned short* o_ckv, unsigned short* o_q,
                                              unsigned short* o_kv, unsigned short* o_f1, unsigned short* o_f2,
                                              unsigned short* o_dwk, unsigned short* o_dwf)
{
    int i = blockIdx.x*256 + threadIdx.x;
    if (i < 147456) {                       // cq: CO=64 CI=256 KS=3
        int tap = i/16384, rem = i%16384, co = rem>>8, ci = rem&255;
        o_cq[i] = f2b(cq[(size_t)(co*256+ci)*9 + tap]);
    } else if (i < 294912) {                // ckv
        int e = i-147456;
        int tap = e/16384, rem = e%16384, co = rem>>8, ci = rem&255;
        o_ckv[e] = f2b(ckv[(size_t)(co*256+ci)*9 + tap]);
    } else if (i < 331776) {                // q: 64x64x3x3
        int e = i-294912;
        int tap = e/4096, rem = e%4096, co = rem>>6, ci = rem&63;
        o_q[e] = f2b(q[(size_t)(co*64+ci)*9 + tap]);
    } else if (i < 339968) {                // kv 1x1: 128x64
        int e = i-331776; o_kv[e] = f2b(kv[e]);
    } else if (i < 471040) {                // ffn1 1x1: 256x512
        int e = i-339968; o_f1[e] = f2b(f1[e]);
    } else if (i < 536576) {                // ffn2 1x1: 256x256
        int e = i-471040; o_f2[e] = f2b(f2[e]);
    } else if (i < 537728) {                // kv depthwise: [tap][128]
        int e = i-536576; int tap = e >> 7, ch = e & 127;
        o_dwk[e] = f2b(dwk[ch*9 + tap]);
    } else if (i < 540032) {                // ffn depthwise: [tap][256]
        int e = i-537728; int tap = e >> 8, ch = e & 255;
        o_dwf[e] = f2b(dwf[ch*9 + tap]);
    }
}

// ---------------- unified MFMA conv (KS=3 pad1 or KS=1), NHWC bf16 ----------------
// BM=128 px; block 256 thr = 4 waves (WM x WN); BN co per block.
// A staged in LDS as [kgrp4][row][px][8ci]; B read from prepacked [tap][COUT][CINT] global.
// OUTM 0: bf16 NHWC (stride so). OUTM 1: fp32 NCHW (KS=1 only).
template<int C0, int C1, int COUT, int KS, int WM, int WN, int BN, int OUTM>
__global__ __launch_bounds__(256) void mconv_k(const unsigned short* __restrict__ in0, int s0,
                                               const unsigned short* __restrict__ in1, int s1,
                                               const unsigned short* __restrict__ wp, long wpbs,
                                               void* __restrict__ outp, int so)
{
    constexpr int CINT = C0 + C1;
    constexpr int KB   = CINT / 32;
    constexpr int MT   = 128 / (16*WM);
    constexpr int NT   = BN / (16*WN);
    constexpr int RWS  = (KS==3) ? 4 : 1;
    constexpr int PXS  = (KS==3) ? 66 : 128;
    constexpr int NTR  = RWS*PXS*4;
    constexpr int ASZ  = 4*RWS*PXS*8;
    constexpr int ESZ  = (OUTM==0) ? 128*BN : 0;
    __shared__ alignas(16) unsigned short sbuf[(ASZ > ESZ) ? ASZ : ESZ];

    const int t = threadIdx.x;
    const int b = blockIdx.z;
    const int cob = blockIdx.y * BN;
    const size_t pb = (size_t)b * HW_;
    int y0 = 0, x0 = 0; size_t p0 = 0;
    if (KS==3) { y0 = (blockIdx.x >> 1) * 2; x0 = (blockIdx.x & 1) * 64; }
    else       { p0 = (size_t)blockIdx.x * 128; }

    const int l = t & 63, w = t >> 6;
    const int wy = w / WN, wx = w % WN;
    const int lrow = l & 15, lk = l >> 4;
    const unsigned short* wpb = wp + (size_t)b * wpbs;

    f32x4 acc[MT][NT] = {};

    for (int kb = 0; kb < KB; ++kb) {
        const int cg = kb*32;
        for (int i = t; i < NTR; i += 256) {
            int g = i & 3, pr = i >> 2;
            int px = pr % PXS, row = pr / PXS;
            uint4 v = {0,0,0,0};
            if (KS==3) {
                int gy = y0 + row - 1, gx = x0 + px - 1;
                if ((unsigned)gy < (unsigned)H_ && (unsigned)gx < (unsigned)W_) {
                    size_t p = (size_t)gy*W_ + gx;
                    int c = cg + g*8;
                    const unsigned short* sp = (c < C0) ? in0 + (pb+p)*s0 + c
                                                        : in1 + (pb+p)*s1 + (c - C0);
                    v = *(const uint4*)sp;
                }
            } else {
                size_t p = p0 + px;
                int c = cg + g*8;
                const unsigned short* sp = (c < C0) ? in0 + (pb+p)*s0 + c
                                                    : in1 + (pb+p)*s1 + (c - C0);
                v = *(const uint4*)sp;
            }
            *(uint4*)&sbuf[((g*RWS + row)*PXS + px)*8] = v;
        }
        __syncthreads();
        #pragma unroll
        for (int tap = 0; tap < KS*KS; ++tap) {
            const int ky = tap/KS, kx = tap%KS;
            short8 bf[NT];
            #pragma unroll
            for (int n = 0; n < NT; ++n) {
                int co = cob + wx*(16*NT) + n*16 + lrow;
                bf[n] = *(const short8*)(wpb + ((size_t)(tap*COUT + co))*CINT + cg + lk*8);
            }
            short8 af[MT];
            #pragma unroll
            for (int m = 0; m < MT; ++m) {
                int pl = wy*(16*MT) + m*16 + lrow;
                int addr;
                if (KS==3) {
                    int r = (pl>>6) + ky, xx = (pl&63) + kx;
                    addr = ((lk*RWS + r)*PXS + xx)*8;
                } else {
                    addr = (lk*RWS*PXS + pl)*8;
                }
                af[m] = *(const short8*)&sbuf[addr];
            }
            #pragma unroll
            for (int m = 0; m < MT; ++m)
                #pragma unroll
                for (int n = 0; n < NT; ++n)
                    acc[m][n] = __builtin_amdgcn_mfma_f32_16x16x32_bf16(af[m], bf[n], acc[m][n], 0, 0, 0);
        }
        __syncthreads();
    }

    if (OUTM == 0) {
        unsigned short* out = (unsigned short*)outp;
        #pragma unroll
        for (int m = 0; m < MT; ++m)
            #pragma unroll
            for (int n = 0; n < NT; ++n) {
                int co = wx*(16*NT) + n*16 + lrow;
                #pragma unroll
                for (int r = 0; r < 4; ++r) {
                    int pl = wy*(16*MT) + m*16 + lk*4 + r;
                    sbuf[pl*BN + co] = f2b(acc[m][n][r]);
                }
            }
        __syncthreads();
        for (int i = t; i < 128*BN/8; i += 256) {
            int pl = i / (BN/8), c8 = (i % (BN/8))*8;
            size_t p = (KS==3) ? ((size_t)(y0 + (pl>>6))*W_ + (size_t)(x0 + (pl&63))) : (p0 + pl);
            *(uint4*)(out + (pb + p)*so + cob + c8) = *(uint4*)&sbuf[pl*BN + c8];
        }
    } else {
        float* out = (float*)outp;
        #pragma unroll
        for (int m = 0; m < MT; ++m)
            #pragma unroll
            for (int n = 0; n < NT; ++n) {
                int co = cob + wx*(16*NT) + n*16 + lrow;
                size_t p = p0 + (size_t)(wy*(16*MT) + m*16 + lk*4);
                *(f32x4*)(out + ((size_t)(b*COUT + co))*HW_ + p) = acc[m][n];
            }
    }
}

// ---------------- channel LayerNorm over C (NHWC bf16, in place, coalesced) ----------------
// C/8 adjacent lanes cooperate on one pixel; shfl_xor reduce; single pass.
// grid = P_*(C/8)/256
template<int C>
__global__ __launch_bounds__(256) void cln_k(unsigned short* __restrict__ io,
                                             const float* __restrict__ wg,
                                             const float* __restrict__ bi)
{
    constexpr int L = C/8;
    size_t idx = (size_t)blockIdx.x*256 + threadIdx.x;
    int sub = (int)(idx % L);
    size_t pix = idx / L;
    unsigned short* rp = io + pix*C + (size_t)sub*8;
    uint4 raw = *(const uint4*)rp;
    float f[8]; up8(raw, f);
    float s = 0.f, ss = 0.f;
    #pragma unroll
    for (int j = 0; j < 8; ++j) { s += f[j]; ss += f[j]*f[j]; }
    #pragma unroll
    for (int m = 1; m < L; m <<= 1) { s += __shfl_xor(s, m); ss += __shfl_xor(ss, m); }
    float mu = s*(1.f/C);
    float rs = rsqrtf(ss*(1.f/C) - mu*mu + 1e-5f);
    float4 w0 = *(const float4*)(wg + sub*8), w1 = *(const float4*)(wg + sub*8 + 4);
    float4 b0 = *(const float4*)(bi + sub*8), b1 = *(const float4*)(bi + sub*8 + 4);
    float o[8];
    o[0]=(f[0]-mu)*rs*w0.x+b0.x; o[1]=(f[1]-mu)*rs*w0.y+b0.y;
    o[2]=(f[2]-mu)*rs*w0.z+b0.z; o[3]=(f[3]-mu)*rs*w0.w+b0.w;
    o[4]=(f[4]-mu)*rs*w1.x+b1.x; o[5]=(f[5]-mu)*rs*w1.y+b1.y;
    o[6]=(f[6]-mu)*rs*w1.z+b1.z; o[7]=(f[7]-mu)*rs*w1.w+b1.w;
    *(uint4*)rp = pk8(o);
}

// ---------------- depthwise 3x3 NHWC bf16 (+GELU), prepacked [tap][CH] bf16 weights ----------------
template<int CH, bool GELU>
__global__ __launch_bounds__(256) void dw_k(const unsigned short* __restrict__ in,
                                            const unsigned short* __restrict__ wp,
                                            unsigned short* __restrict__ out)
{
    size_t idx = (size_t)blockIdx.x*256 + threadIdx.x;   // over P_*(CH/8)
    int c8 = (int)(idx % (CH/8));
    size_t pix = idx / (CH/8);
    int p = (int)(pix % HW_);
    size_t pb = pix - p;
    int yy = p >> 7, xx = p & 127;
    float wf[9][8];
    #pragma unroll
    for (int tap = 0; tap < 9; ++tap) {
        uint4 r = *(const uint4*)(wp + tap*CH + c8*8);
        up8(r, wf[tap]);
    }
    float a[8] = {0,0,0,0,0,0,0,0};
    #pragma unroll
    for (int ky = 0; ky < 3; ++ky) {
        int gy = yy + ky - 1;
        if ((unsigned)gy >= (unsigned)H_) continue;
        #pragma unroll
        for (int kx = 0; kx < 3; ++kx) {
            int gx = xx + kx - 1;
            if ((unsigned)gx >= (unsigned)W_) continue;
            uint4 r = *(const uint4*)(in + (pb + (size_t)gy*W_ + gx)*CH + c8*8);
            float f[8]; up8(r, f);
            #pragma unroll
            for (int j = 0; j < 8; ++j) a[j] += f[j]*wf[ky*3+kx][j];
        }
    }
    if (GELU) {
        #pragma unroll
        for (int j = 0; j < 8; ++j) a[j] = 0.5f*a[j]*(1.f + erff(a[j]*0.70710678118654752f));
    }
    *(uint4*)(out + pix*CH + c8*8) = pk8(a);
}

// ---------------- attention probs per (b,h) ----------------
__global__ __launch_bounds__(256) void attn_k(const unsigned short* __restrict__ qc,
                                              const unsigned short* __restrict__ kvd,
                                              const float* __restrict__ temp,
                                              float* __restrict__ probs)
{
    int b = blockIdx.x >> 3, h = blockIdx.x & 7;
    int t = threadIdx.x;
    const unsigned short* qb = qc  + (size_t)b*HW_*64  + h*8;
    const unsigned short* kb = kvd + (size_t)b*HW_*128 + h*8;
    float qs[8] = {}, ks[8] = {}, dt[8][8] = {{}};
    for (int p = t; p < HW_; p += 256) {
        float qv[8], kv[8];
        up8(*(const uint4*)(qb + (size_t)p*64),  qv);
        up8(*(const uint4*)(kb + (size_t)p*128), kv);
        #pragma unroll
        for (int i = 0; i < 8; ++i) { qs[i] += qv[i]*qv[i]; ks[i] += kv[i]*kv[i]; }
        #pragma unroll
        for (int i = 0; i < 8; ++i)
            #pragma unroll
            for (int j = 0; j < 8; ++j) dt[i][j] += qv[i]*kv[j];
    }
    __shared__ float red[4][80];
    __shared__ float fin[80];
    int lane = t & 63, wv = t >> 6;
    #pragma unroll
    for (int i = 0; i < 8; ++i) { float v = qs[i]; for (int m=1;m<64;m<<=1) v += __shfl_xor(v,m); if (!lane) red[wv][i] = v; }
    #pragma unroll
    for (int i = 0; i < 8; ++i) { float v = ks[i]; for (int m=1;m<64;m<<=1) v += __shfl_xor(v,m); if (!lane) red[wv][8+i] = v; }
    #pragma unroll
    for (int i = 0; i < 8; ++i)
        #pragma unroll
        for (int j = 0; j < 8; ++j) { float v = dt[i][j]; for (int m=1;m<64;m<<=1) v += __shfl_xor(v,m); if (!lane) red[wv][16+i*8+j] = v; }
    __syncthreads();
    if (t < 80) fin[t] = red[0][t] + red[1][t] + red[2][t] + red[3][t];
    __syncthreads();
    if (t < 8) {
        int i = t;
        float qn = fmaxf(sqrtf(fin[i]), 1e-12f);
        float tm = temp[h];
        float lg[8]; float mx = -1e30f;
        #pragma unroll
        for (int j = 0; j < 8; ++j) {
            float kn = fmaxf(sqrtf(fin[8+j]), 1e-12f);
            lg[j] = fin[16+i*8+j] / (qn*kn) * tm;
            mx = fmaxf(mx, lg[j]);
        }
        float se = 0.f;
        #pragma unroll
        for (int j = 0; j < 8; ++j) { lg[j] = expf(lg[j]-mx); se += lg[j]; }
        float inv = 1.f/se;
        #pragma unroll
        for (int j = 0; j < 8; ++j) probs[(((size_t)b*8 + h)*8 + i)*8 + j] = lg[j]*inv;
    }
}

// ---------------- Mb = w_po . blockdiag(attn)  [8][64][64] ----------------
__global__ __launch_bounds__(256) void mb_k(const float* __restrict__ probs,
                                            const float* __restrict__ wpo,
                                            float* __restrict__ Mb)
{
    int b = blockIdx.x;
    for (int o = threadIdx.x; o < 4096; o += 256) {
        int co = o >> 6, d = o & 63, h = d >> 3, j = d & 7;
        float s = 0.f;
        #pragma unroll
        for (int i2 = 0; i2 < 8; ++i2)
            s += wpo[co*64 + h*8 + i2] * probs[(((size_t)b*8 + h)*8 + i2)*8 + j];
        Mb[(size_t)b*4096 + o] = s;
    }
}

// ---------------- weff[b][tap][eo][d] = sum_c w_expand[eo][c][tap] * Mb[b][c][d] ----------------
__global__ __launch_bounds__(256) void weff_k(const float* __restrict__ Mb,
                                              const float* __restrict__ wex,
                                              unsigned short* __restrict__ weff)
{
    int b = blockIdx.x / 576;
    int i = (blockIdx.x % 576)*256 + threadIdx.x;   // < 147456
    int tap = i / 16384, rem = i % 16384;
    int eo = rem >> 6, d = rem & 63;
    const float* mb = Mb + (size_t)b*4096;
    float s = 0.f;
    #pragma unroll 8
    for (int c = 0; c < 64; ++c)
        s += wex[(size_t)(eo*64 + c)*9 + tap] * mb[c*64 + d];
    weff[(size_t)b*147456 + i] = f2b(s);
}

extern "C" void kernel_launch(void* const* d_in, const int* in_sizes, int n_in,
                              void* d_out, int out_size, void* d_ws, size_t ws_size,
                              hipStream_t stream) {
    (void)in_sizes; (void)n_in; (void)out_size; (void)ws_size;
    const float* x        = (const float*)d_in[0];
    const float* y        = (const float*)d_in[1];
    const float* w_cq     = (const float*)d_in[2];
    const float* w_ckv    = (const float*)d_in[3];
    const float* ln_q_w   = (const float*)d_in[4];
    const float* ln_q_b   = (const float*)d_in[5];
    const float* ln_kv_w  = (const float*)d_in[6];
    const float* ln_kv_b  = (const float*)d_in[7];
    const float* w_kv     = (const float*)d_in[8];
    const float* w_kvdw   = (const float*)d_in[9];
    const float* w_q      = (const float*)d_in[10];
    const float* temperature = (const float*)d_in[11];
    const float* w_po     = (const float*)d_in[12];
    const float* w_expand = (const float*)d_in[13];
    const float* ln_out_w = (const float*)d_in[14];
    const float* ln_out_b = (const float*)d_in[15];
    const float* w_ffn1   = (const float*)d_in[16];
    const float* w_ffn_dw = (const float*)d_in[17];
    const float* w_ffn2   = (const float*)d_in[18];
    float* outp = (float*)d_out;

    // ---- buffer map (bytes). ws peak use ~118.2 MiB (<= 128 MiB known-safe). ----
    const size_t MB = 1u<<20;
    char* ws8 = (char*)d_ws;
    unsigned short* ykv  = (unsigned short*)(ws8 + 0);        // 16MB, live: ckv..kv1
    unsigned short* kv1  = (unsigned short*)(ws8 + 16*MB);    // 32MB, live: kv1..dw
    unsigned short* kvd  = (unsigned short*)(ws8 + 80*MB);    // 32MB, live: dw..expand
    unsigned short* xq   = (unsigned short*)(ws8 + 0);        // 16MB, live: cq..qconv
    unsigned short* qc   = (unsigned short*)(ws8 + 16*MB);    // 16MB, live: qconv..attn
    unsigned short* vexp = (unsigned short*)(ws8 + 0);        // 64MB, live: expand..ffn1
    unsigned short* f2b_ = (unsigned short*)(ws8 + 0);        // 64MB, live: dw2..ffn2
    float* probs = (float*)(ws8 + 112*MB);                    // 16KB
    float* Mb    = (float*)(ws8 + 113*MB);                    // 128KB
    unsigned short* weff = (unsigned short*)(ws8 + 114*MB);   // 2.25MB
    unsigned short* wpB  = (unsigned short*)(ws8 + 117*MB);   // 1.08MB static prepacked
    unsigned short* wp_cq  = wpB;
    unsigned short* wp_ckv = wpB + 147456;
    unsigned short* wp_q   = wpB + 294912;
    unsigned short* wp_kv  = wpB + 331776;
    unsigned short* wp_f1  = wpB + 339968;
    unsigned short* wp_f2  = wpB + 471040;
    unsigned short* wp_dwk = wpB + 536576;   // [tap][128]
    unsigned short* wp_dwf = wpB + 537728;   // [tap][256]
    // d_out as scratch: xb [0,64MB), yb/f1 [64,128MB)
    unsigned short* xb = (unsigned short*)d_out;
    unsigned short* yb = (unsigned short*)d_out + 32*MB;      // elements (64MB offset)
    unsigned short* f1 = yb;

    const unsigned short* NUL = (const unsigned short*)nullptr;

    // 0. prepack static weights + pack y
    prep_k<<<2110, 256, 0, stream>>>(w_cq, w_ckv, w_q, w_kv, w_ffn1, w_ffn2, w_kvdw, w_ffn_dw,
                                     wp_cq, wp_ckv, wp_q, wp_kv, wp_f1, wp_f2, wp_dwk, wp_dwf);
    pack_k<<<dim3(256,4,8), 256, 0, stream>>>(y, yb);
    // 1. ykv = LN(conv3x3(yb, ckv))
    mconv_k<256,0,64,3,4,1,64,0><<<dim3(128,1,8), 256, 0, stream>>>(yb,256, NUL,0, wp_ckv,0, ykv,64);
    cln_k<64><<<4096, 256, 0, stream>>>(ykv, ln_kv_w, ln_kv_b);
    // 2. kv1 = conv1x1(ykv); kvd = dw3x3(kv1)
    mconv_k<64,0,128,1,2,2,128,0><<<dim3(128,1,8), 256, 0, stream>>>(ykv,64, NUL,0, wp_kv,0, kv1,128);
    dw_k<128,false><<<8192, 256, 0, stream>>>(kv1, wp_dwk, kvd);
    // 3. pack x; xq = LN(conv3x3(xb, cq)); qc = conv3x3(xq, q)
    pack_k<<<dim3(256,4,8), 256, 0, stream>>>(x, xb);
    mconv_k<256,0,64,3,4,1,64,0><<<dim3(128,1,8), 256, 0, stream>>>(xb,256, NUL,0, wp_cq,0, xq,64);
    cln_k<64><<<4096, 256, 0, stream>>>(xq, ln_q_w, ln_q_b);
    mconv_k<64,0,64,3,4,1,64,0><<<dim3(128,1,8), 256, 0, stream>>>(xq,64, NUL,0, wp_q,0, qc,64);
    // 4. attention -> probs -> Mb -> per-batch effective expand weights
    attn_k<<<64, 256, 0, stream>>>(qc, kvd, temperature, probs);
    mb_k<<<8, 256, 0, stream>>>(probs, w_po, Mb);
    weff_k<<<4608, 256, 0, stream>>>(Mb, w_expand, weff);
    // 5. vexp = LN(conv3x3(v, weff_b))   (fused attn@v + project_out + expand)
    mconv_k<64,0,256,3,2,2,128,0><<<dim3(128,2,8), 256, 0, stream>>>(kvd+64,128, NUL,0, weff,147456, vexp,256);
    cln_k<256><<<16384, 256, 0, stream>>>(vexp, ln_out_w, ln_out_b);
    // 6. f1 = conv1x1([xb, vn], ffn1); f2 = gelu(dw3x3(f1)); out = conv1x1(f2, ffn2) fp32 NCHW
    mconv_k<256,256,256,1,2,2,128,0><<<dim3(128,2,8), 256, 0, stream>>>(xb,256, vexp,256, wp_f1,0, f1,256);
    dw_k<256,true><<<16384, 256, 0, stream>>>(f1, wp_dwf, f2b_);
    mconv_k<256,0,256,1,2,2,128,1><<<dim3(128,2,8), 256, 0, stream>>>(f2b_,256, NUL,0, wp_f2,0, outp,0);
}

// Round 5
// 825.722 us; speedup vs baseline: 6.2034x; 1.0782x over previous
//
#include <hip/hip_runtime.h>
#include <hip/hip_bf16.h>
#include <math.h>

#define B_ 8
#define C_ 256
#define S_ 64
#define H_ 128
#define W_ 128
#define HW_ (H_*W_)
#define P_ (B_*HW_)

typedef __attribute__((ext_vector_type(8))) short short8;
typedef __attribute__((ext_vector_type(4))) float f32x4;

__device__ __forceinline__ unsigned short f2b(float f){
    __hip_bfloat16 h = __float2bfloat16(f);
    return *reinterpret_cast<unsigned short*>(&h);
}
__device__ __forceinline__ void up8(uint4 u, float* f){
    unsigned v0=u.x,v1=u.y,v2=u.z,v3=u.w;
    f[0]=__uint_as_float(v0<<16); f[1]=__uint_as_float(v0&0xffff0000u);
    f[2]=__uint_as_float(v1<<16); f[3]=__uint_as_float(v1&0xffff0000u);
    f[4]=__uint_as_float(v2<<16); f[5]=__uint_as_float(v2&0xffff0000u);
    f[6]=__uint_as_float(v3<<16); f[7]=__uint_as_float(v3&0xffff0000u);
}
__device__ __forceinline__ uint4 pk8(const float* f){
    uint4 u;
    u.x = (unsigned)f2b(f[0]) | ((unsigned)f2b(f[1])<<16);
    u.y = (unsigned)f2b(f[2]) | ((unsigned)f2b(f[3])<<16);
    u.z = (unsigned)f2b(f[4]) | ((unsigned)f2b(f[5])<<16);
    u.w = (unsigned)f2b(f[6]) | ((unsigned)f2b(f[7])<<16);
    return u;
}

// ---------------- NCHW fp32 -> NHWC bf16 pack (fused x+y via z) ----------------
// grid (HW/64, C/64, 16): z<8 -> inA(b=z), z>=8 -> inB(b=z-8)
__global__ __launch_bounds__(256) void pack_k(const float* __restrict__ inA,
                                              const float* __restrict__ inB,
                                              unsigned short* __restrict__ outA,
                                              unsigned short* __restrict__ outB)
{
    __shared__ unsigned short tl[64][72];
    const int t = threadIdx.x;
    const int p0 = blockIdx.x*64, c0 = blockIdx.y*64;
    const int sel = blockIdx.z >> 3, b = blockIdx.z & 7;
    const float* in = sel ? inB : inA;
    unsigned short* out = sel ? outB : outA;
    const float* ib = in + ((size_t)b*C_ + c0)*HW_ + p0;
    for (int i = t; i < 1024; i += 256){
        int ci = i >> 4, px = (i & 15)*4;
        float4 v = *(const float4*)(ib + (size_t)ci*HW_ + px);
        tl[px+0][ci]=f2b(v.x); tl[px+1][ci]=f2b(v.y); tl[px+2][ci]=f2b(v.z); tl[px+3][ci]=f2b(v.w);
    }
    __syncthreads();
    unsigned short* ob = out + ((size_t)b*HW_ + p0)*C_ + c0;
    for (int i = t; i < 512; i += 256){
        int px = i >> 3, c8 = (i & 7)*8;
        *(uint4*)(ob + (size_t)px*C_ + c8) = *(uint4*)&tl[px][c8];
    }
}

// ---------------- weight prepack: fragment-major [tap][coT][kb][lane][8] ----------------
__device__ __forceinline__ void packw(const float* __restrict__ src, unsigned short* __restrict__ dst,
                                      int e, int CO, int CI, int KS2)
{
    int KB = CI/32;
    int tap = e / (CO*CI);
    int rem = e % (CO*CI);
    int coT = rem / (CI*16);
    int rem2 = rem % (CI*16);
    int kb = rem2 >> 9;
    int l  = (rem2 >> 3) & 63;
    int ee = rem2 & 7;
    int co = coT*16 + (l & 15);
    int ci = kb*32 + (l >> 4)*8 + ee;
    float v = (KS2==9) ? src[(size_t)(co*CI+ci)*9 + tap] : src[(size_t)co*CI + ci];
    dst[e] = f2b(v);
}

// total = 536576 gemm + 1152 dwk + 2304 dwf = 540032 ; grid 2110 x 256
__global__ __launch_bounds__(256) void prep_k(const float* __restrict__ cq, const float* __restrict__ ckv,
                                              const float* __restrict__ q,  const float* __restrict__ kv,
                                              const float* __restrict__ f1, const float* __restrict__ f2,
                                              const float* __restrict__ dwk, const float* __restrict__ dwf,
                                              unsigned short* o_cq, unsigned short* o_ckv, unsigned short* o_q,
                                              unsigned short* o_kv, unsigned short* o_f1, unsigned short* o_f2,
                                              unsigned short* o_dwk, unsigned short* o_dwf)
{
    int i = blockIdx.x*256 + threadIdx.x;
    if      (i < 147456) packw(cq,  o_cq,  i,          64, 256, 9);
    else if (i < 294912) packw(ckv, o_ckv, i-147456,   64, 256, 9);
    else if (i < 331776) packw(q,   o_q,   i-294912,   64,  64, 9);
    else if (i < 339968) packw(kv,  o_kv,  i-331776,  128,  64, 1);
    else if (i < 471040) packw(f1,  o_f1,  i-339968,  256, 512, 1);
    else if (i < 536576) packw(f2,  o_f2,  i-471040,  256, 256, 1);
    else if (i < 537728) { int e=i-536576; o_dwk[e] = f2b(dwk[(e&127)*9 + (e>>7)]); }
    else if (i < 540032) { int e=i-537728; o_dwf[e] = f2b(dwf[(e&255)*9 + (e>>8)]); }
}

// ---------------- MFMA conv: A+B LDS-staged, T14 reg-prefetch, 2 barriers/kb ----------------
// BM=128 px; 256 thr = 4 waves (WM x WN); BN co/block; fused alt set via blockIdx.z>=8.
template<int C0,int C1,int COUT,int KS,int WM,int WN,int BN,int OUTM>
__global__ __launch_bounds__(256) void mconv_k(
    const unsigned short* __restrict__ in0, int s0,
    const unsigned short* __restrict__ in1, int s1,
    const unsigned short* __restrict__ wp, long wpbs,
    void* __restrict__ outp, int so,
    const unsigned short* __restrict__ in0B,
    const unsigned short* __restrict__ wpB2,
    void* __restrict__ outB)
{
    constexpr int CINT = C0+C1;
    constexpr int KB  = CINT/32;
    constexpr int MT  = 128/(16*WM);
    constexpr int NT  = BN/(16*WN);
    constexpr int RWS = (KS==3)?4:1;
    constexpr int PXS = (KS==3)?66:128;
    constexpr int NTR = RWS*PXS*4;            // uint4 staging count (A)
    constexpr int NLD = (NTR+255)/256;
    constexpr int ASZ = RWS*PXS*32;           // shorts
    constexpr int BSZ = KS*KS*(BN/16)*512;    // shorts
    constexpr int NB  = BSZ/8/256;            // uint4 staging count per thread (B)
    constexpr int CSZ = ASZ + BSZ;
    constexpr int ESZ = (OUTM==0)?128*BN:0;
    constexpr int SSZ = (CSZ>ESZ)?CSZ:ESZ;
    __shared__ alignas(16) unsigned short sbuf[SSZ];
    unsigned short* sA = sbuf;
    unsigned short* sB = sbuf + ASZ;

    const int t = threadIdx.x;
    const int sel = blockIdx.z >> 3;
    const int b   = blockIdx.z & 7;
    const int cob = blockIdx.y*BN;
    const size_t pb = (size_t)b*HW_;
    const unsigned short* pin0 = sel ? in0B : in0;
    const unsigned short* wpb  = (sel ? wpB2 : wp) + (size_t)b*wpbs;

    int y0=0,x0=0; size_t p0=0;
    if (KS==3){ y0=(blockIdx.x>>1)*2; x0=(blockIdx.x&1)*64; }
    else p0 = (size_t)blockIdx.x*128;

    const int l = t&63, w = t>>6;
    const int wy = w/WN, wx = w%WN;
    const int lrow = l&15, lk = l>>4;

    uint4 rga[NLD];
    uint4 rgb[NB];

    auto loadA = [&](int kb){
        const int cg = kb*32;
        #pragma unroll
        for (int j=0;j<NLD;++j){
            int i = t + j*256;
            if (NLD*256==NTR || i<NTR){
                int g = i&3, pr = i>>2;
                int px = pr%PXS, row = pr/PXS;
                uint4 v = {0,0,0,0};
                int c = cg + g*8;
                if (KS==3){
                    int gy = y0+row-1, gx = x0+px-1;
                    if ((unsigned)gy<(unsigned)H_ && (unsigned)gx<(unsigned)W_){
                        size_t p = (size_t)gy*W_+gx;
                        const unsigned short* sp = (c<C0)? pin0+(pb+p)*s0+c : in1+(pb+p)*s1+(c-C0);
                        v = *(const uint4*)sp;
                    }
                } else {
                    size_t p = p0+px;
                    const unsigned short* sp = (c<C0)? pin0+(pb+p)*s0+c : in1+(pb+p)*s1+(c-C0);
                    v = *(const uint4*)sp;
                }
                rga[j] = v;
            }
        }
    };
    auto storeA = [&](){
        #pragma unroll
        for (int j=0;j<NLD;++j){
            int i = t + j*256;
            if (NLD*256==NTR || i<NTR){
                int g=i&3, pr=i>>2;
                int px=pr%PXS, row=pr/PXS;
                *(uint4*)&sA[(row*PXS+px)*32 + ((g^(px&3))<<3)] = rga[j];
            }
        }
    };
    auto loadB = [&](int kb){
        #pragma unroll
        for (int j=0;j<NB;++j){
            int i = t + j*256;
            int floc = i>>6, li = i&63;
            int tap = floc/(BN/16), nloc = floc%(BN/16);
            int fi = (tap*(COUT/16) + (cob>>4) + nloc)*KB + kb;
            rgb[j] = *(const uint4*)(wpb + (size_t)fi*512 + li*8);
        }
    };
    auto storeB = [&](){
        #pragma unroll
        for (int j=0;j<NB;++j){
            int i = t + j*256;
            *(uint4*)&sB[i*8] = rgb[j];
        }
    };

    f32x4 acc[MT][NT] = {};
    loadA(0); loadB(0);
    for (int kb=0; kb<KB; ++kb){
        __syncthreads();
        storeA(); storeB();
        __syncthreads();
        if (kb+1<KB){ loadA(kb+1); loadB(kb+1); }
        #pragma unroll
        for (int tap=0; tap<KS*KS; ++tap){
            const int ky=tap/KS, kx=tap%KS;
            short8 bf[NT];
            #pragma unroll
            for (int n=0;n<NT;++n)
                bf[n] = *(const short8*)&sB[((tap*(BN/16)+wx*NT+n)*64 + l)*8];
            short8 af[MT];
            #pragma unroll
            for (int m=0;m<MT;++m){
                int pl = wy*(16*MT)+m*16+lrow;
                int addr;
                if (KS==3){
                    int r=(pl>>6)+ky, xx=(pl&63)+kx;
                    addr = (r*PXS+xx)*32 + ((lk^(xx&3))<<3);
                } else {
                    addr = pl*32 + ((lk^(pl&3))<<3);
                }
                af[m] = *(const short8*)&sA[addr];
            }
            #pragma unroll
            for (int m=0;m<MT;++m)
                #pragma unroll
                for (int n=0;n<NT;++n)
                    acc[m][n] = __builtin_amdgcn_mfma_f32_16x16x32_bf16(af[m],bf[n],acc[m][n],0,0,0);
        }
    }
    __syncthreads();

    if (OUTM==0){
        unsigned short* out = (unsigned short*)(sel ? outB : outp);
        #pragma unroll
        for (int m=0;m<MT;++m)
            #pragma unroll
            for (int n=0;n<NT;++n){
                int co = wx*(16*NT)+n*16+lrow;
                #pragma unroll
                for (int r=0;r<4;++r){
                    int pl = wy*(16*MT)+m*16+lk*4+r;
                    sbuf[pl*BN+co] = f2b(acc[m][n][r]);
                }
            }
        __syncthreads();
        for (int i=t; i<128*BN/8; i+=256){
            int pl = i/(BN/8), c8 = (i%(BN/8))*8;
            size_t p = (KS==3) ? ((size_t)(y0+(pl>>6))*W_ + (size_t)(x0+(pl&63))) : (p0+pl);
            *(uint4*)(out + (pb+p)*so + cob + c8) = *(uint4*)&sbuf[pl*BN+c8];
        }
    } else {
        float* out = (float*)(sel ? outB : outp);
        #pragma unroll
        for (int m=0;m<MT;++m)
            #pragma unroll
            for (int n=0;n<NT;++n){
                int co = cob + wx*(16*NT)+n*16+lrow;
                size_t p = p0 + (size_t)(wy*(16*MT)+m*16+lk*4);
                *(f32x4*)(out + ((size_t)(b*COUT+co))*HW_ + p) = acc[m][n];
            }
    }
}

// ---------------- channel LayerNorm (NHWC bf16, coalesced, shfl group) ----------------
template<int C>
__global__ __launch_bounds__(256) void cln_k(unsigned short* __restrict__ io,
                                             const float* __restrict__ wg,
                                             const float* __restrict__ bi)
{
    constexpr int L = C/8;
    size_t idx = (size_t)blockIdx.x*256 + threadIdx.x;
    int sub = (int)(idx % L);
    size_t pix = idx / L;
    unsigned short* rp = io + pix*C + (size_t)sub*8;
    uint4 raw = *(const uint4*)rp;
    float f[8]; up8(raw, f);
    float s = 0.f, ss = 0.f;
    #pragma unroll
    for (int j=0;j<8;++j){ s += f[j]; ss += f[j]*f[j]; }
    #pragma unroll
    for (int m=1;m<L;m<<=1){ s += __shfl_xor(s,m); ss += __shfl_xor(ss,m); }
    float mu = s*(1.f/C);
    float rs = rsqrtf(ss*(1.f/C) - mu*mu + 1e-5f);
    float4 w0 = *(const float4*)(wg+sub*8), w1 = *(const float4*)(wg+sub*8+4);
    float4 b0 = *(const float4*)(bi+sub*8), b1 = *(const float4*)(bi+sub*8+4);
    float o[8];
    o[0]=(f[0]-mu)*rs*w0.x+b0.x; o[1]=(f[1]-mu)*rs*w0.y+b0.y;
    o[2]=(f[2]-mu)*rs*w0.z+b0.z; o[3]=(f[3]-mu)*rs*w0.w+b0.w;
    o[4]=(f[4]-mu)*rs*w1.x+b1.x; o[5]=(f[5]-mu)*rs*w1.y+b1.y;
    o[6]=(f[6]-mu)*rs*w1.z+b1.z; o[7]=(f[7]-mu)*rs*w1.w+b1.w;
    *(uint4*)rp = pk8(o);
}

// ---------------- depthwise 3x3 NHWC bf16 (+GELU), prepacked [tap][CH] bf16 weights ----------------
template<int CH, bool GELU>
__global__ __launch_bounds__(256) void dw_k(const unsigned short* __restrict__ in,
                                            const unsigned short* __restrict__ wp,
                                            unsigned short* __restrict__ out)
{
    size_t idx = (size_t)blockIdx.x*256 + threadIdx.x;
    int c8 = (int)(idx % (CH/8));
    size_t pix = idx / (CH/8);
    int p = (int)(pix % HW_);
    size_t pb = pix - p;
    int yy = p >> 7, xx = p & 127;
    float wf[9][8];
    #pragma unroll
    for (int tap=0; tap<9; ++tap){
        uint4 r = *(const uint4*)(wp + tap*CH + c8*8);
        up8(r, wf[tap]);
    }
    float a[8] = {0,0,0,0,0,0,0,0};
    #pragma unroll
    for (int ky=0; ky<3; ++ky){
        int gy = yy+ky-1;
        if ((unsigned)gy >= (unsigned)H_) continue;
        #pragma unroll
        for (int kx=0; kx<3; ++kx){
            int gx = xx+kx-1;
            if ((unsigned)gx >= (unsigned)W_) continue;
            uint4 r = *(const uint4*)(in + (pb + (size_t)gy*W_ + gx)*CH + c8*8);
            float f[8]; up8(r, f);
            #pragma unroll
            for (int j=0;j<8;++j) a[j] += f[j]*wf[ky*3+kx][j];
        }
    }
    if (GELU){
        #pragma unroll
        for (int j=0;j<8;++j) a[j] = 0.5f*a[j]*(1.f + erff(a[j]*0.70710678118654752f));
    }
    *(uint4*)(out + pix*CH + c8*8) = pk8(a);
}

// ---------------- attention probs per (b,h) ----------------
__global__ __launch_bounds__(256) void attn_k(const unsigned short* __restrict__ qc,
                                              const unsigned short* __restrict__ kvd,
                                              const float* __restrict__ temp,
                                              float* __restrict__ probs)
{
    int b = blockIdx.x >> 3, h = blockIdx.x & 7;
    int t = threadIdx.x;
    const unsigned short* qb = qc  + (size_t)b*HW_*64  + h*8;
    const unsigned short* kb = kvd + (size_t)b*HW_*128 + h*8;
    float qs[8] = {}, ks[8] = {}, dt[8][8] = {{}};
    for (int p = t; p < HW_; p += 256){
        float qv[8], kv[8];
        up8(*(const uint4*)(qb + (size_t)p*64),  qv);
        up8(*(const uint4*)(kb + (size_t)p*128), kv);
        #pragma unroll
        for (int i=0;i<8;++i){ qs[i]+=qv[i]*qv[i]; ks[i]+=kv[i]*kv[i]; }
        #pragma unroll
        for (int i=0;i<8;++i)
            #pragma unroll
            for (int j=0;j<8;++j) dt[i][j] += qv[i]*kv[j];
    }
    __shared__ float red[4][80];
    __shared__ float fin[80];
    int lane = t & 63, wv = t >> 6;
    #pragma unroll
    for (int i=0;i<8;++i){ float v=qs[i]; for (int m=1;m<64;m<<=1) v += __shfl_xor(v,m); if(!lane) red[wv][i]=v; }
    #pragma unroll
    for (int i=0;i<8;++i){ float v=ks[i]; for (int m=1;m<64;m<<=1) v += __shfl_xor(v,m); if(!lane) red[wv][8+i]=v; }
    #pragma unroll
    for (int i=0;i<8;++i)
        #pragma unroll
        for (int j=0;j<8;++j){ float v=dt[i][j]; for (int m=1;m<64;m<<=1) v += __shfl_xor(v,m); if(!lane) red[wv][16+i*8+j]=v; }
    __syncthreads();
    if (t < 80) fin[t] = red[0][t]+red[1][t]+red[2][t]+red[3][t];
    __syncthreads();
    if (t < 8){
        int i = t;
        float qn = fmaxf(sqrtf(fin[i]), 1e-12f);
        float tm = temp[h];
        float lg[8]; float mx = -1e30f;
        #pragma unroll
        for (int j=0;j<8;++j){
            float kn = fmaxf(sqrtf(fin[8+j]), 1e-12f);
            lg[j] = fin[16+i*8+j]/(qn*kn)*tm;
            mx = fmaxf(mx, lg[j]);
        }
        float se = 0.f;
        #pragma unroll
        for (int j=0;j<8;++j){ lg[j]=expf(lg[j]-mx); se+=lg[j]; }
        float inv = 1.f/se;
        #pragma unroll
        for (int j=0;j<8;++j) probs[(((size_t)b*8+h)*8+i)*8+j] = lg[j]*inv;
    }
}

// ---------------- Mb = w_po . blockdiag(attn)  [8][64][64] ----------------
__global__ __launch_bounds__(256) void mb_k(const float* __restrict__ probs,
                                            const float* __restrict__ wpo,
                                            float* __restrict__ Mb)
{
    int b = blockIdx.x;
    for (int o = threadIdx.x; o < 4096; o += 256){
        int co = o >> 6, d = o & 63, h = d >> 3, j = d & 7;
        float s = 0.f;
        #pragma unroll
        for (int i2=0;i2<8;++i2)
            s += wpo[co*64 + h*8 + i2] * probs[(((size_t)b*8+h)*8+i2)*8 + j];
        Mb[(size_t)b*4096 + o] = s;
    }
}

// ---------------- weff: fragment-major per-batch expand weights (COUT=256, CI=64, KS=3) ----------------
__global__ __launch_bounds__(256) void weff_k(const float* __restrict__ Mb,
                                              const float* __restrict__ wex,
                                              unsigned short* __restrict__ weff)
{
    int b = blockIdx.x / 576;
    int i = (blockIdx.x % 576)*256 + threadIdx.x;   // < 147456
    int tap = i / 16384;
    int rem = i % 16384;
    int coT = rem / 1024;
    int rem2 = rem % 1024;
    int kb = rem2 >> 9;
    int l  = (rem2 >> 3) & 63;
    int ee = rem2 & 7;
    int eo = coT*16 + (l & 15);
    int d  = kb*32 + (l >> 4)*8 + ee;
    const float* mb = Mb + (size_t)b*4096;
    float s = 0.f;
    #pragma unroll 8
    for (int c=0;c<64;++c)
        s += wex[(size_t)(eo*64+c)*9 + tap] * mb[c*64 + d];
    weff[(size_t)b*147456 + i] = f2b(s);
}

extern "C" void kernel_launch(void* const* d_in, const int* in_sizes, int n_in,
                              void* d_out, int out_size, void* d_ws, size_t ws_size,
                              hipStream_t stream) {
    (void)in_sizes; (void)n_in; (void)out_size; (void)ws_size;
    const float* x        = (const float*)d_in[0];
    const float* y        = (const float*)d_in[1];
    const float* w_cq     = (const float*)d_in[2];
    const float* w_ckv    = (const float*)d_in[3];
    const float* ln_q_w   = (const float*)d_in[4];
    const float* ln_q_b   = (const float*)d_in[5];
    const float* ln_kv_w  = (const float*)d_in[6];
    const float* ln_kv_b  = (const float*)d_in[7];
    const float* w_kv     = (const float*)d_in[8];
    const float* w_kvdw   = (const float*)d_in[9];
    const float* w_q      = (const float*)d_in[10];
    const float* temperature = (const float*)d_in[11];
    const float* w_po     = (const float*)d_in[12];
    const float* w_expand = (const float*)d_in[13];
    const float* ln_out_w = (const float*)d_in[14];
    const float* ln_out_b = (const float*)d_in[15];
    const float* w_ffn1   = (const float*)d_in[16];
    const float* w_ffn_dw = (const float*)d_in[17];
    const float* w_ffn2   = (const float*)d_in[18];
    float* outp = (float*)d_out;

    // ---- buffer map (bytes). ws peak ~118.2 MiB. ----
    const size_t MB = 1u<<20;
    char* ws8 = (char*)d_ws;
    unsigned short* ykv  = (unsigned short*)(ws8 + 0);        // 16MB  live: conv..kv1
    unsigned short* xq   = (unsigned short*)(ws8 + 16*MB);    // 16MB  live: conv..q
    unsigned short* kv1  = (unsigned short*)(ws8 + 32*MB);    // 32MB  live: kv1..dw
    unsigned short* qc   = (unsigned short*)(ws8 + 64*MB);    // 16MB  live: q..attn
    unsigned short* kvd  = (unsigned short*)(ws8 + 80*MB);    // 32MB  live: dw..expand
    unsigned short* vexp = (unsigned short*)(ws8 + 0);        // 64MB  live: expand..ffn1
    unsigned short* f2b_ = (unsigned short*)(ws8 + 0);        // 64MB  live: dw2..ffn2
    float* probs = (float*)(ws8 + 112*MB);
    float* Mb    = (float*)(ws8 + 113*MB);
    unsigned short* weff = (unsigned short*)(ws8 + 114*MB);   // 2.25MB
    unsigned short* wpB  = (unsigned short*)(ws8 + 117*MB);   // ~1.08MB
    unsigned short* wp_cq  = wpB;
    unsigned short* wp_ckv = wpB + 147456;
    unsigned short* wp_q   = wpB + 294912;
    unsigned short* wp_kv  = wpB + 331776;
    unsigned short* wp_f1  = wpB + 339968;
    unsigned short* wp_f2  = wpB + 471040;
    unsigned short* wp_dwk = wpB + 536576;
    unsigned short* wp_dwf = wpB + 537728;
    unsigned short* xb = (unsigned short*)d_out;              // d_out[0,64MB)
    unsigned short* yb = (unsigned short*)d_out + 32*MB;      // d_out[64,128MB)
    unsigned short* f1 = yb;

    const unsigned short* NUL = (const unsigned short*)nullptr;

    prep_k<<<2110, 256, 0, stream>>>(w_cq, w_ckv, w_q, w_kv, w_ffn1, w_ffn2, w_kvdw, w_ffn_dw,
                                     wp_cq, wp_ckv, wp_q, wp_kv, wp_f1, wp_f2, wp_dwk, wp_dwf);
    pack_k<<<dim3(256,4,16), 256, 0, stream>>>(y, x, yb, xb);
    // fused: z<8 -> ckv(yb->ykv), z>=8 -> cq(xb->xq)
    mconv_k<256,0,64,3,4,1,64,0><<<dim3(128,1,16), 256, 0, stream>>>(yb,256, NUL,0, wp_ckv,0, ykv,64, xb, wp_cq, xq);
    cln_k<64><<<4096, 256, 0, stream>>>(ykv, ln_kv_w, ln_kv_b);
    cln_k<64><<<4096, 256, 0, stream>>>(xq, ln_q_w, ln_q_b);
    mconv_k<64,0,128,1,2,2,128,0><<<dim3(128,1,8), 256, 0, stream>>>(ykv,64, NUL,0, wp_kv,0, kv1,128, ykv, wp_kv, kv1);
    mconv_k<64,0,64,3,4,1,64,0><<<dim3(128,1,8), 256, 0, stream>>>(xq,64, NUL,0, wp_q,0, qc,64, xq, wp_q, qc);
    dw_k<128,false><<<8192, 256, 0, stream>>>(kv1, wp_dwk, kvd);
    attn_k<<<64, 256, 0, stream>>>(qc, kvd, temperature, probs);
    mb_k<<<8, 256, 0, stream>>>(probs, w_po, Mb);
    weff_k<<<4608, 256, 0, stream>>>(Mb, w_expand, weff);
    // fused attn@v + project_out + expand: per-batch weights weff
    mconv_k<64,0,256,3,4,1,64,0><<<dim3(128,4,8), 256, 0, stream>>>(kvd+64,128, NUL,0, weff,147456, vexp,256, kvd+64, weff, vexp);
    cln_k<256><<<16384, 256, 0, stream>>>(vexp, ln_out_w, ln_out_b);
    mconv_k<256,256,256,1,2,2,128,0><<<dim3(128,2,8), 256, 0, stream>>>(xb,256, vexp,256, wp_f1,0, f1,256, xb, wp_f1, f1);
    dw_k<256,true><<<16384, 256, 0, stream>>>(f1, wp_dwf, f2b_);
    mconv_k<256,0,256,1,2,2,128,1><<<dim3(128,2,8), 256, 0, stream>>>(f2b_,256, NUL,0, wp_f2,0, outp,0, f2b_, wp_f2, outp);
}

// Round 6
// 617.032 us; speedup vs baseline: 8.3014x; 1.3382x over previous
//
#include <hip/hip_runtime.h>
#include <hip/hip_bf16.h>
#include <math.h>

#define B_ 8
#define C_ 256
#define S_ 64
#define H_ 128
#define W_ 128
#define HW_ (H_*W_)
#define P_ (B_*HW_)

typedef __attribute__((ext_vector_type(8))) short short8;
typedef __attribute__((ext_vector_type(4))) float f32x4;

__device__ __forceinline__ unsigned short f2b(float f){
    __hip_bfloat16 h = __float2bfloat16(f);
    return *reinterpret_cast<unsigned short*>(&h);
}
__device__ __forceinline__ void up8(uint4 u, float* f){
    unsigned v0=u.x,v1=u.y,v2=u.z,v3=u.w;
    f[0]=__uint_as_float(v0<<16); f[1]=__uint_as_float(v0&0xffff0000u);
    f[2]=__uint_as_float(v1<<16); f[3]=__uint_as_float(v1&0xffff0000u);
    f[4]=__uint_as_float(v2<<16); f[5]=__uint_as_float(v2&0xffff0000u);
    f[6]=__uint_as_float(v3<<16); f[7]=__uint_as_float(v3&0xffff0000u);
}
__device__ __forceinline__ uint4 pk8(const float* f){
    uint4 u;
    u.x = (unsigned)f2b(f[0]) | ((unsigned)f2b(f[1])<<16);
    u.y = (unsigned)f2b(f[2]) | ((unsigned)f2b(f[3])<<16);
    u.z = (unsigned)f2b(f[4]) | ((unsigned)f2b(f[5])<<16);
    u.w = (unsigned)f2b(f[6]) | ((unsigned)f2b(f[7])<<16);
    return u;
}
// async global->LDS, 16B per lane
__device__ __forceinline__ void gl2lds(const unsigned short* g, unsigned short* l){
    __builtin_amdgcn_global_load_lds((const __attribute__((address_space(1))) void*)g,
                                     (__attribute__((address_space(3))) void*)l, 16, 0, 0);
}

// ---------------- NCHW fp32 -> NHWC bf16 pack (fused x+y via z) ----------------
__global__ __launch_bounds__(256) void pack_k(const float* __restrict__ inA,
                                              const float* __restrict__ inB,
                                              unsigned short* __restrict__ outA,
                                              unsigned short* __restrict__ outB)
{
    __shared__ unsigned short tl[64][72];
    const int t = threadIdx.x;
    const int p0 = blockIdx.x*64, c0 = blockIdx.y*64;
    const int sel = blockIdx.z >> 3, b = blockIdx.z & 7;
    const float* in = sel ? inB : inA;
    unsigned short* out = sel ? outB : outA;
    const float* ib = in + ((size_t)b*C_ + c0)*HW_ + p0;
    for (int i = t; i < 1024; i += 256){
        int ci = i >> 4, px = (i & 15)*4;
        float4 v = *(const float4*)(ib + (size_t)ci*HW_ + px);
        tl[px+0][ci]=f2b(v.x); tl[px+1][ci]=f2b(v.y); tl[px+2][ci]=f2b(v.z); tl[px+3][ci]=f2b(v.w);
    }
    __syncthreads();
    unsigned short* ob = out + ((size_t)b*HW_ + p0)*C_ + c0;
    for (int i = t; i < 512; i += 256){
        int px = i >> 3, c8 = (i & 7)*8;
        *(uint4*)(ob + (size_t)px*C_ + c8) = *(uint4*)&tl[px][c8];
    }
}

// ---------------- weight prepack: fragment-major [tap][coT][kb][lane][8] ----------------
__device__ __forceinline__ void packw(const float* __restrict__ src, unsigned short* __restrict__ dst,
                                      int e, int CO, int CI, int KS2)
{
    int KB = CI/32;
    int tap = e / (CO*CI);
    int rem = e % (CO*CI);
    int coT = rem / (CI*16);
    int rem2 = rem % (CI*16);
    int kb = rem2 >> 9;
    int l  = (rem2 >> 3) & 63;
    int ee = rem2 & 7;
    int co = coT*16 + (l & 15);
    int ci = kb*32 + (l >> 4)*8 + ee;
    float v = (KS2==9) ? src[(size_t)(co*CI+ci)*9 + tap] : src[(size_t)co*CI + ci];
    dst[e] = f2b(v);
}

// total = 536576 gemm + 1152 dwk + 2304 dwf + 8 zero = 540040 ; grid 2111 x 256
__global__ __launch_bounds__(256) void prep_k(const float* __restrict__ cq, const float* __restrict__ ckv,
                                              const float* __restrict__ q,  const float* __restrict__ kv,
                                              const float* __restrict__ f1, const float* __restrict__ f2,
                                              const float* __restrict__ dwk, const float* __restrict__ dwf,
                                              unsigned short* o_cq, unsigned short* o_ckv, unsigned short* o_q,
                                              unsigned short* o_kv, unsigned short* o_f1, unsigned short* o_f2,
                                              unsigned short* o_dwk, unsigned short* o_dwf)
{
    int i = blockIdx.x*256 + threadIdx.x;
    if      (i < 147456) packw(cq,  o_cq,  i,          64, 256, 9);
    else if (i < 294912) packw(ckv, o_ckv, i-147456,   64, 256, 9);
    else if (i < 331776) packw(q,   o_q,   i-294912,   64,  64, 9);
    else if (i < 339968) packw(kv,  o_kv,  i-331776,  128,  64, 1);
    else if (i < 471040) packw(f1,  o_f1,  i-339968,  256, 512, 1);
    else if (i < 536576) packw(f2,  o_f2,  i-471040,  256, 256, 1);
    else if (i < 537728) { int e=i-536576; o_dwk[e] = f2b(dwk[(e&127)*9 + (e>>7)]); }
    else if (i < 540032) { int e=i-537728; o_dwf[e] = f2b(dwf[(e&255)*9 + (e>>8)]); }
    else if (i < 540040) { o_dwf[i-537728] = 0; }   // 16B zero page for OOB halo
}

// ---------------- MFMA conv: A via global_load_lds dbuf, B direct from L2, BN=64 ----------------
// 256 thr = 4 waves (2M x 2N); MT=4, NT=2. fused alt set via blockIdx.z>=8.
// OUTM 0: bf16 NHWC. OUTM 1: fp32 NCHW via LDS transpose (coalesced 512B rows).
// LNF 1: fused channel-LayerNorm epilogue (requires COUT==64).
template<int C0,int C1,int COUT,int KS,int OUTM,int LNF>
__global__ __launch_bounds__(256,4) void mconv_k(
    const unsigned short* __restrict__ in0, int s0,
    const unsigned short* __restrict__ in1, int s1,
    const unsigned short* __restrict__ wp, long wpbs,
    void* __restrict__ outp, int so,
    const unsigned short* __restrict__ in0B,
    const unsigned short* __restrict__ wpB2,
    void* __restrict__ outB,
    const unsigned short* __restrict__ zbuf,
    const float* __restrict__ lnw0, const float* __restrict__ lnb0,
    const float* __restrict__ lnw1, const float* __restrict__ lnb1)
{
    constexpr int CINT = C0+C1;
    constexpr int KB  = CINT/32;
    constexpr int MT  = 4;
    constexpr int NT  = 2;
    constexpr int RWS = (KS==3)?4:1;
    constexpr int PXS = (KS==3)?66:128;
    constexpr int NTR = RWS*PXS*4;            // uint4 count per kb
    constexpr int NLD = (NTR+255)/256;
    constexpr int ASZ = RWS*PXS*32;           // shorts per buffer
    constexpr int EP  = (OUTM==1) ? 64*132*2 : 128*64;   // shorts
    constexpr int SSZ = (2*ASZ > EP) ? 2*ASZ : EP;
    __shared__ alignas(16) unsigned short sbuf[SSZ];

    const int t = threadIdx.x;
    const int sel = blockIdx.z >> 3;
    const int b   = blockIdx.z & 7;
    const int cob = blockIdx.y*64;
    const size_t pb = (size_t)b*HW_;
    const unsigned short* pin0 = sel ? in0B : in0;
    const unsigned short* wpb  = (sel ? wpB2 : wp) + (size_t)b*wpbs;

    int y0=0,x0=0; size_t p0=0;
    if (KS==3){ y0=(blockIdx.x>>1)*2; x0=(blockIdx.x&1)*64; }
    else p0 = (size_t)blockIdx.x*128;

    const int l = t&63, w = t>>6;
    const int wy = w>>1, wx = w&1;
    const int lrow = l&15, lk = l>>4;

    auto issueA = [&](int kb, int bsel){
        const int cg = kb*32;
        unsigned short* dst = sbuf + bsel*ASZ;
        #pragma unroll
        for (int j=0;j<NLD;++j){
            int i = t + j*256;
            if ((NTR%256)==0 || j<NLD-1 || i<NTR){
                int slot = i&3, pr = i>>2;
                int px = pr%PXS, row = pr/PXS;
                int g = slot ^ (px&3);
                int c = cg + g*8;
                const unsigned short* sp;
                if (KS==3){
                    int gy = y0+row-1, gx = x0+px-1;
                    bool ok = ((unsigned)gy<(unsigned)H_) & ((unsigned)gx<(unsigned)W_);
                    size_t p = (size_t)gy*W_+gx;
                    const unsigned short* base = (c<C0)? pin0+(pb+p)*s0+c : in1+(pb+p)*s1+(c-C0);
                    sp = ok ? base : zbuf;
                } else {
                    size_t p = p0+px;
                    sp = (c<C0)? pin0+(pb+p)*s0+c : in1+(pb+p)*s1+(c-C0);
                }
                gl2lds(sp, dst + (size_t)i*8);
            }
        }
    };
    auto loadB = [&](short8* dst, int kb, int tap){
        #pragma unroll
        for (int n=0;n<NT;++n){
            int fi = (tap*(COUT/16) + (cob>>4) + wx*NT + n)*KB + kb;
            dst[n] = *(const short8*)(wpb + (size_t)fi*512 + l*8);
        }
    };

    f32x4 acc[MT][NT] = {};

    if (KS==3){
        short8 bfs[3][NT];
        issueA(0,0);
        loadB(bfs[0],0,0); loadB(bfs[1],0,1); loadB(bfs[2],0,2);
        for (int kb=0; kb<KB; ++kb){
            __syncthreads();
            unsigned short* cur = sbuf + (kb&1)*ASZ;
            #pragma unroll
            for (int tap=0;tap<9;++tap){
                const int ky=tap/3, kx=tap%3;
                if (tap==2 && kb+1<KB) issueA(kb+1,(kb+1)&1);
                short8 af[MT];
                #pragma unroll
                for (int m=0;m<MT;++m){
                    int pl = wy*64 + m*16 + lrow;
                    int r = (pl>>6)+ky, xx = (pl&63)+kx;
                    af[m] = *(const short8*)&cur[((r*PXS+xx)*4 + (lk^(xx&3)))*8];
                }
                #pragma unroll
                for (int m=0;m<MT;++m)
                    #pragma unroll
                    for (int n=0;n<NT;++n)
                        acc[m][n] = __builtin_amdgcn_mfma_f32_16x16x32_bf16(af[m],bfs[tap%3][n],acc[m][n],0,0,0);
                if (tap+3 < 9)      loadB(bfs[tap%3], kb, tap+3);
                else if (kb+1<KB)   loadB(bfs[tap%3], kb+1, tap-6);
            }
        }
    } else {
        short8 bfs[2][NT];
        issueA(0,0);
        loadB(bfs[0],0,0); if (KB>1) loadB(bfs[1],1,0);
        auto step1 = [&](int kb, short8 (&bcur)[NT]){
            __syncthreads();
            unsigned short* cur = sbuf + (kb&1)*ASZ;
            if (kb+1<KB) issueA(kb+1,(kb+1)&1);
            short8 af[MT];
            #pragma unroll
            for (int m=0;m<MT;++m){
                int pl = wy*64 + m*16 + lrow;
                af[m] = *(const short8*)&cur[(pl*4 + (lk^(pl&3)))*8];
            }
            #pragma unroll
            for (int m=0;m<MT;++m)
                #pragma unroll
                for (int n=0;n<NT;++n)
                    acc[m][n] = __builtin_amdgcn_mfma_f32_16x16x32_bf16(af[m],bcur[n],acc[m][n],0,0,0);
            if (kb+2<KB) loadB(bcur, kb+2, 0);
        };
        for (int kb2=0; kb2<KB; kb2+=2){
            step1(kb2,   bfs[0]);
            step1(kb2+1, bfs[1]);
        }
    }
    __syncthreads();

    if (OUTM==1){
        float* sf = (float*)sbuf;
        #pragma unroll
        for (int m=0;m<MT;++m)
            #pragma unroll
            for (int n=0;n<NT;++n){
                int co_l = wx*32 + n*16 + lrow;
                int pl0  = wy*64 + m*16 + lk*4;
                *(f32x4*)&sf[co_l*132 + pl0] = acc[m][n];
            }
        __syncthreads();
        float* out = (float*)(sel ? outB : outp);
        for (int i=t; i<2048; i+=256){
            int co = i>>5, pxg = i&31;
            f32x4 v = *(const f32x4*)&sf[co*132 + pxg*4];
            *(f32x4*)(out + ((size_t)(b*COUT + cob + co))*HW_ + p0 + pxg*4) = v;
        }
    } else if (LNF){
        // swizzled store: group slot = (co>>3) ^ (pl&7)
        #pragma unroll
        for (int m=0;m<MT;++m)
            #pragma unroll
            for (int n=0;n<NT;++n){
                int co = wx*32 + n*16 + lrow;
                int grp = co>>3, cr = co&7;
                #pragma unroll
                for (int r=0;r<4;++r){
                    int pl = wy*64 + m*16 + lk*4 + r;
                    sbuf[pl*64 + ((grp^(pl&7))<<3) + cr] = f2b(acc[m][n][r]);
                }
            }
        __syncthreads();
        if (t < 128){
            int pl = t;
            uint4 raw[8];
            float s = 0.f, ss = 0.f;
            #pragma unroll
            for (int j=0;j<8;++j){
                raw[j] = *(const uint4*)&sbuf[pl*64 + ((j^(pl&7))<<3)];
                float f[8]; up8(raw[j], f);
                #pragma unroll
                for (int k=0;k<8;++k){ s += f[k]; ss += f[k]*f[k]; }
            }
            float mu = s*(1.f/64.f);
            float rs = rsqrtf(ss*(1.f/64.f) - mu*mu + 1e-5f);
            const float* lw = sel ? lnw1 : lnw0;
            const float* lb = sel ? lnb1 : lnb0;
            unsigned short* out = (unsigned short*)(sel ? outB : outp);
            size_t p = (size_t)(y0+(pl>>6))*W_ + x0 + (pl&63);
            unsigned short* orow = out + (pb+p)*64;
            #pragma unroll
            for (int j=0;j<8;++j){
                float f[8], o[8];
                up8(raw[j], f);
                #pragma unroll
                for (int k=0;k<8;++k) o[k] = (f[k]-mu)*rs*lw[j*8+k] + lb[j*8+k];
                *(uint4*)(orow + j*8) = pk8(o);
            }
        }
    } else {
        unsigned short* out = (unsigned short*)(sel ? outB : outp);
        #pragma unroll
        for (int m=0;m<MT;++m)
            #pragma unroll
            for (int n=0;n<NT;++n){
                int co = wx*32 + n*16 + lrow;
                #pragma unroll
                for (int r=0;r<4;++r){
                    int pl = wy*64 + m*16 + lk*4 + r;
                    sbuf[pl*64 + co] = f2b(acc[m][n][r]);
                }
            }
        __syncthreads();
        for (int i=t; i<1024; i+=256){
            int pl = i>>3, c8 = (i&7)*8;
            size_t p = (KS==3) ? ((size_t)(y0+(pl>>6))*W_ + (size_t)(x0+(pl&63))) : (p0+pl);
            *(uint4*)(out + (pb+p)*so + cob + c8) = *(uint4*)&sbuf[pl*64 + c8];
        }
    }
}

// ---------------- channel LayerNorm (NHWC bf16, coalesced, shfl group) ----------------
template<int C>
__global__ __launch_bounds__(256) void cln_k(unsigned short* __restrict__ io,
                                             const float* __restrict__ wg,
                                             const float* __restrict__ bi)
{
    constexpr int L = C/8;
    size_t idx = (size_t)blockIdx.x*256 + threadIdx.x;
    int sub = (int)(idx % L);
    size_t pix = idx / L;
    unsigned short* rp = io + pix*C + (size_t)sub*8;
    uint4 raw = *(const uint4*)rp;
    float f[8]; up8(raw, f);
    float s = 0.f, ss = 0.f;
    #pragma unroll
    for (int j=0;j<8;++j){ s += f[j]; ss += f[j]*f[j]; }
    #pragma unroll
    for (int m=1;m<L;m<<=1){ s += __shfl_xor(s,m); ss += __shfl_xor(ss,m); }
    float mu = s*(1.f/C);
    float rs = rsqrtf(ss*(1.f/C) - mu*mu + 1e-5f);
    float4 w0 = *(const float4*)(wg+sub*8), w1 = *(const float4*)(wg+sub*8+4);
    float4 b0 = *(const float4*)(bi+sub*8), b1 = *(const float4*)(bi+sub*8+4);
    float o[8];
    o[0]=(f[0]-mu)*rs*w0.x+b0.x; o[1]=(f[1]-mu)*rs*w0.y+b0.y;
    o[2]=(f[2]-mu)*rs*w0.z+b0.z; o[3]=(f[3]-mu)*rs*w0.w+b0.w;
    o[4]=(f[4]-mu)*rs*w1.x+b1.x; o[5]=(f[5]-mu)*rs*w1.y+b1.y;
    o[6]=(f[6]-mu)*rs*w1.z+b1.z; o[7]=(f[7]-mu)*rs*w1.w+b1.w;
    *(uint4*)rp = pk8(o);
}

// ---------------- depthwise 3x3 NHWC bf16 (+GELU), prepacked [tap][CH] weights ----------------
template<int CH, bool GELU>
__global__ __launch_bounds__(256) void dw_k(const unsigned short* __restrict__ in,
                                            const unsigned short* __restrict__ wp,
                                            unsigned short* __restrict__ out)
{
    size_t idx = (size_t)blockIdx.x*256 + threadIdx.x;
    int c8 = (int)(idx % (CH/8));
    size_t pix = idx / (CH/8);
    int p = (int)(pix % HW_);
    size_t pb = pix - p;
    int yy = p >> 7, xx = p & 127;
    float wf[9][8];
    #pragma unroll
    for (int tap=0; tap<9; ++tap){
        uint4 r = *(const uint4*)(wp + tap*CH + c8*8);
        up8(r, wf[tap]);
    }
    float a[8] = {0,0,0,0,0,0,0,0};
    #pragma unroll
    for (int ky=0; ky<3; ++ky){
        int gy = yy+ky-1;
        if ((unsigned)gy >= (unsigned)H_) continue;
        #pragma unroll
        for (int kx=0; kx<3; ++kx){
            int gx = xx+kx-1;
            if ((unsigned)gx >= (unsigned)W_) continue;
            uint4 r = *(const uint4*)(in + (pb + (size_t)gy*W_ + gx)*CH + c8*8);
            float f[8]; up8(r, f);
            #pragma unroll
            for (int j=0;j<8;++j) a[j] += f[j]*wf[ky*3+kx][j];
        }
    }
    if (GELU){
        #pragma unroll
        for (int j=0;j<8;++j) a[j] = 0.5f*a[j]*(1.f + erff(a[j]*0.70710678118654752f));
    }
    *(uint4*)(out + pix*CH + c8*8) = pk8(a);
}

// ---------------- attention probs per (b,h) ----------------
__global__ __launch_bounds__(256) void attn_k(const unsigned short* __restrict__ qc,
                                              const unsigned short* __restrict__ kvd,
                                              const float* __restrict__ temp,
                                              float* __restrict__ probs)
{
    int b = blockIdx.x >> 3, h = blockIdx.x & 7;
    int t = threadIdx.x;
    const unsigned short* qb = qc  + (size_t)b*HW_*64  + h*8;
    const unsigned short* kb = kvd + (size_t)b*HW_*128 + h*8;
    float qs[8] = {}, ks[8] = {}, dt[8][8] = {{}};
    for (int p = t; p < HW_; p += 256){
        float qv[8], kv[8];
        up8(*(const uint4*)(qb + (size_t)p*64),  qv);
        up8(*(const uint4*)(kb + (size_t)p*128), kv);
        #pragma unroll
        for (int i=0;i<8;++i){ qs[i]+=qv[i]*qv[i]; ks[i]+=kv[i]*kv[i]; }
        #pragma unroll
        for (int i=0;i<8;++i)
            #pragma unroll
            for (int j=0;j<8;++j) dt[i][j] += qv[i]*kv[j];
    }
    __shared__ float red[4][80];
    __shared__ float fin[80];
    int lane = t & 63, wv = t >> 6;
    #pragma unroll
    for (int i=0;i<8;++i){ float v=qs[i]; for (int m=1;m<64;m<<=1) v += __shfl_xor(v,m); if(!lane) red[wv][i]=v; }
    #pragma unroll
    for (int i=0;i<8;++i){ float v=ks[i]; for (int m=1;m<64;m<<=1) v += __shfl_xor(v,m); if(!lane) red[wv][8+i]=v; }
    #pragma unroll
    for (int i=0;i<8;++i)
        #pragma unroll
        for (int j=0;j<8;++j){ float v=dt[i][j]; for (int m=1;m<64;m<<=1) v += __shfl_xor(v,m); if(!lane) red[wv][16+i*8+j]=v; }
    __syncthreads();
    if (t < 80) fin[t] = red[0][t]+red[1][t]+red[2][t]+red[3][t];
    __syncthreads();
    if (t < 8){
        int i = t;
        float qn = fmaxf(sqrtf(fin[i]), 1e-12f);
        float tm = temp[h];
        float lg[8]; float mx = -1e30f;
        #pragma unroll
        for (int j=0;j<8;++j){
            float kn = fmaxf(sqrtf(fin[8+j]), 1e-12f);
            lg[j] = fin[16+i*8+j]/(qn*kn)*tm;
            mx = fmaxf(mx, lg[j]);
        }
        float se = 0.f;
        #pragma unroll
        for (int j=0;j<8;++j){ lg[j]=expf(lg[j]-mx); se+=lg[j]; }
        float inv = 1.f/se;
        #pragma unroll
        for (int j=0;j<8;++j) probs[(((size_t)b*8+h)*8+i)*8+j] = lg[j]*inv;
    }
}

// ---------------- Mb = w_po . blockdiag(attn)  [8][64][64] ----------------
__global__ __launch_bounds__(256) void mb_k(const float* __restrict__ probs,
                                            const float* __restrict__ wpo,
                                            float* __restrict__ Mb)
{
    int b = blockIdx.x;
    for (int o = threadIdx.x; o < 4096; o += 256){
        int co = o >> 6, d = o & 63, h = d >> 3, j = d & 7;
        float s = 0.f;
        #pragma unroll
        for (int i2=0;i2<8;++i2)
            s += wpo[co*64 + h*8 + i2] * probs[(((size_t)b*8+h)*8+i2)*8 + j];
        Mb[(size_t)b*4096 + o] = s;
    }
}

// ---------------- weff: fragment-major per-batch expand weights (COUT=256, CI=64, KS=3) ----------------
__global__ __launch_bounds__(256) void weff_k(const float* __restrict__ Mb,
                                              const float* __restrict__ wex,
                                              unsigned short* __restrict__ weff)
{
    int b = blockIdx.x / 576;
    int i = (blockIdx.x % 576)*256 + threadIdx.x;   // < 147456
    int tap = i / 16384;
    int rem = i % 16384;
    int coT = rem / 1024;
    int rem2 = rem % 1024;
    int kb = rem2 >> 9;
    int l  = (rem2 >> 3) & 63;
    int ee = rem2 & 7;
    int eo = coT*16 + (l & 15);
    int d  = kb*32 + (l >> 4)*8 + ee;
    const float* mb = Mb + (size_t)b*4096;
    float s = 0.f;
    #pragma unroll 8
    for (int c=0;c<64;++c)
        s += wex[(size_t)(eo*64+c)*9 + tap] * mb[c*64 + d];
    weff[(size_t)b*147456 + i] = f2b(s);
}

extern "C" void kernel_launch(void* const* d_in, const int* in_sizes, int n_in,
                              void* d_out, int out_size, void* d_ws, size_t ws_size,
                              hipStream_t stream) {
    (void)in_sizes; (void)n_in; (void)out_size; (void)ws_size;
    const float* x        = (const float*)d_in[0];
    const float* y        = (const float*)d_in[1];
    const float* w_cq     = (const float*)d_in[2];
    const float* w_ckv    = (const float*)d_in[3];
    const float* ln_q_w   = (const float*)d_in[4];
    const float* ln_q_b   = (const float*)d_in[5];
    const float* ln_kv_w  = (const float*)d_in[6];
    const float* ln_kv_b  = (const float*)d_in[7];
    const float* w_kv     = (const float*)d_in[8];
    const float* w_kvdw   = (const float*)d_in[9];
    const float* w_q      = (const float*)d_in[10];
    const float* temperature = (const float*)d_in[11];
    const float* w_po     = (const float*)d_in[12];
    const float* w_expand = (const float*)d_in[13];
    const float* ln_out_w = (const float*)d_in[14];
    const float* ln_out_b = (const float*)d_in[15];
    const float* w_ffn1   = (const float*)d_in[16];
    const float* w_ffn_dw = (const float*)d_in[17];
    const float* w_ffn2   = (const float*)d_in[18];
    float* outp = (float*)d_out;

    const size_t MB = 1u<<20;
    char* ws8 = (char*)d_ws;
    unsigned short* ykv  = (unsigned short*)(ws8 + 0);        // 16MB
    unsigned short* xq   = (unsigned short*)(ws8 + 16*MB);    // 16MB
    unsigned short* kv1  = (unsigned short*)(ws8 + 32*MB);    // 32MB
    unsigned short* qc   = (unsigned short*)(ws8 + 64*MB);    // 16MB
    unsigned short* kvd  = (unsigned short*)(ws8 + 80*MB);    // 32MB
    unsigned short* vexp = (unsigned short*)(ws8 + 0);        // 64MB
    unsigned short* f2b_ = (unsigned short*)(ws8 + 0);        // 64MB
    float* probs = (float*)(ws8 + 112*MB);
    float* Mb    = (float*)(ws8 + 113*MB);
    unsigned short* weff = (unsigned short*)(ws8 + 114*MB);   // 2.25MB
    unsigned short* wpB  = (unsigned short*)(ws8 + 117*MB);
    unsigned short* wp_cq  = wpB;
    unsigned short* wp_ckv = wpB + 147456;
    unsigned short* wp_q   = wpB + 294912;
    unsigned short* wp_kv  = wpB + 331776;
    unsigned short* wp_f1  = wpB + 339968;
    unsigned short* wp_f2  = wpB + 471040;
    unsigned short* wp_dwk = wpB + 536576;
    unsigned short* wp_dwf = wpB + 537728;
    unsigned short* zbuf   = wpB + 540032;                    // 16B zeros
    unsigned short* xb = (unsigned short*)d_out;              // d_out[0,64MB)
    unsigned short* yb = (unsigned short*)d_out + 32*MB;      // d_out[64,128MB)
    unsigned short* f1 = yb;

    const unsigned short* NUL = (const unsigned short*)nullptr;

    prep_k<<<2111, 256, 0, stream>>>(w_cq, w_ckv, w_q, w_kv, w_ffn1, w_ffn2, w_kvdw, w_ffn_dw,
                                     wp_cq, wp_ckv, wp_q, wp_kv, wp_f1, wp_f2, wp_dwk, wp_dwf);
    pack_k<<<dim3(256,4,16), 256, 0, stream>>>(y, x, yb, xb);
    // fused cq+ckv with in-epilogue LayerNorm: z<8 -> ckv(yb->ykv, ln_kv), z>=8 -> cq(xb->xq, ln_q)
    mconv_k<256,0,64,3,0,1><<<dim3(128,1,16), 256, 0, stream>>>(yb,256, NUL,0, wp_ckv,0, ykv,64,
        xb, wp_cq, xq, zbuf, ln_kv_w, ln_kv_b, ln_q_w, ln_q_b);
    mconv_k<64,0,128,1,0,0><<<dim3(128,2,8), 256, 0, stream>>>(ykv,64, NUL,0, wp_kv,0, kv1,128,
        ykv, wp_kv, kv1, zbuf, NULL,NULL,NULL,NULL);
    mconv_k<64,0,64,3,0,0><<<dim3(128,1,8), 256, 0, stream>>>(xq,64, NUL,0, wp_q,0, qc,64,
        xq, wp_q, qc, zbuf, NULL,NULL,NULL,NULL);
    dw_k<128,false><<<8192, 256, 0, stream>>>(kv1, wp_dwk, kvd);
    attn_k<<<64, 256, 0, stream>>>(qc, kvd, temperature, probs);
    mb_k<<<8, 256, 0, stream>>>(probs, w_po, Mb);
    weff_k<<<4608, 256, 0, stream>>>(Mb, w_expand, weff);
    // fused attn@v + project_out + expand (per-batch weights weff)
    mconv_k<64,0,256,3,0,0><<<dim3(128,4,8), 256, 0, stream>>>(kvd+64,128, NUL,0, weff,147456, vexp,256,
        kvd+64, weff, vexp, zbuf, NULL,NULL,NULL,NULL);
    cln_k<256><<<16384, 256, 0, stream>>>(vexp, ln_out_w, ln_out_b);
    mconv_k<256,256,256,1,0,0><<<dim3(128,4,8), 256, 0, stream>>>(xb,256, vexp,256, wp_f1,0, f1,256,
        xb, wp_f1, f1, zbuf, NULL,NULL,NULL,NULL);
    dw_k<256,true><<<16384, 256, 0, stream>>>(f1, wp_dwf, f2b_);
    // ffn2: fp32 NCHW output, coalesced via LDS transpose
    mconv_k<256,0,256,1,1,0><<<dim3(128,4,8), 256, 0, stream>>>(f2b_,256, NUL,0, wp_f2,0, outp,0,
        f2b_, wp_f2, outp, zbuf, NULL,NULL,NULL,NULL);
}

// Round 7
// 578.099 us; speedup vs baseline: 8.8605x; 1.0673x over previous
//
#include <hip/hip_runtime.h>
#include <hip/hip_bf16.h>
#include <math.h>

#define B_ 8
#define C_ 256
#define S_ 64
#define H_ 128
#define W_ 128
#define HW_ (H_*W_)
#define P_ (B_*HW_)

typedef __attribute__((ext_vector_type(8))) short short8;
typedef __attribute__((ext_vector_type(4))) float f32x4;

__device__ __forceinline__ unsigned short f2b(float f){
    __hip_bfloat16 h = __float2bfloat16(f);
    return *reinterpret_cast<unsigned short*>(&h);
}
__device__ __forceinline__ void up8(uint4 u, float* f){
    unsigned v0=u.x,v1=u.y,v2=u.z,v3=u.w;
    f[0]=__uint_as_float(v0<<16); f[1]=__uint_as_float(v0&0xffff0000u);
    f[2]=__uint_as_float(v1<<16); f[3]=__uint_as_float(v1&0xffff0000u);
    f[4]=__uint_as_float(v2<<16); f[5]=__uint_as_float(v2&0xffff0000u);
    f[6]=__uint_as_float(v3<<16); f[7]=__uint_as_float(v3&0xffff0000u);
}
__device__ __forceinline__ uint4 pk8(const float* f){
    uint4 u;
    u.x = (unsigned)f2b(f[0]) | ((unsigned)f2b(f[1])<<16);
    u.y = (unsigned)f2b(f[2]) | ((unsigned)f2b(f[3])<<16);
    u.z = (unsigned)f2b(f[4]) | ((unsigned)f2b(f[5])<<16);
    u.w = (unsigned)f2b(f[6]) | ((unsigned)f2b(f[7])<<16);
    return u;
}
__device__ __forceinline__ void gl2lds(const unsigned short* g, unsigned short* l){
    __builtin_amdgcn_global_load_lds((const __attribute__((address_space(1))) void*)g,
                                     (__attribute__((address_space(3))) void*)l, 16, 0, 0);
}

// All activations use C32-blocked layout: [b][C/32][HW][32] (bf16).
// addr(b,c,p) = b*C*HW + (c>>5)*HW*32 + p*32 + (c&31)

// ---------------- NCHW fp32 -> blocked bf16 pack (fused x+y via z) ----------------
__global__ __launch_bounds__(256) void pack_k(const float* __restrict__ inA,
                                              const float* __restrict__ inB,
                                              unsigned short* __restrict__ outA,
                                              unsigned short* __restrict__ outB)
{
    __shared__ unsigned short tl[64][72];
    const int t = threadIdx.x;
    const int p0 = blockIdx.x*64, c0 = blockIdx.y*64;
    const int sel = blockIdx.z >> 3, b = blockIdx.z & 7;
    const float* in = sel ? inB : inA;
    unsigned short* out = sel ? outB : outA;
    const float* ib = in + ((size_t)b*C_ + c0)*HW_ + p0;
    for (int i = t; i < 1024; i += 256){
        int ci = i >> 4, px = (i & 15)*4;
        float4 v = *(const float4*)(ib + (size_t)ci*HW_ + px);
        tl[px+0][ci]=f2b(v.x); tl[px+1][ci]=f2b(v.y); tl[px+2][ci]=f2b(v.z); tl[px+3][ci]=f2b(v.w);
    }
    __syncthreads();
    for (int i = t; i < 512; i += 256){
        int px = i >> 3, c8 = (i & 7)*8;
        int cc = c0 + c8;
        unsigned short* dst = out + ((size_t)b*8 + (cc>>5))*(size_t)HW_*32
                                  + (size_t)(p0+px)*32 + (cc&31);
        *(uint4*)dst = *(uint4*)&tl[px][c8];
    }
}

// ---------------- weight prepack: fragment-major [tap][coT][kb][lane][8] ----------------
__device__ __forceinline__ void packw(const float* __restrict__ src, unsigned short* __restrict__ dst,
                                      int e, int CO, int CI, int KS2)
{
    int KB = CI/32;
    int tap = e / (CO*CI);
    int rem = e % (CO*CI);
    int coT = rem / (CI*16);
    int rem2 = rem % (CI*16);
    int kb = rem2 >> 9;
    int l  = (rem2 >> 3) & 63;
    int ee = rem2 & 7;
    int co = coT*16 + (l & 15);
    int ci = kb*32 + (l >> 4)*8 + ee;
    float v = (KS2==9) ? src[(size_t)(co*CI+ci)*9 + tap] : src[(size_t)co*CI + ci];
    dst[e] = f2b(v);
}

__global__ __launch_bounds__(256) void prep_k(const float* __restrict__ cq, const float* __restrict__ ckv,
                                              const float* __restrict__ q,  const float* __restrict__ kv,
                                              const float* __restrict__ f1, const float* __restrict__ f2,
                                              const float* __restrict__ dwk, const float* __restrict__ dwf,
                                              unsigned short* o_cq, unsigned short* o_ckv, unsigned short* o_q,
                                              unsigned short* o_kv, unsigned short* o_f1, unsigned short* o_f2,
                                              unsigned short* o_dwk, unsigned short* o_dwf)
{
    int i = blockIdx.x*256 + threadIdx.x;
    if      (i < 147456) packw(cq,  o_cq,  i,          64, 256, 9);
    else if (i < 294912) packw(ckv, o_ckv, i-147456,   64, 256, 9);
    else if (i < 331776) packw(q,   o_q,   i-294912,   64,  64, 9);
    else if (i < 339968) packw(kv,  o_kv,  i-331776,  128,  64, 1);
    else if (i < 471040) packw(f1,  o_f1,  i-339968,  256, 512, 1);
    else if (i < 536576) packw(f2,  o_f2,  i-471040,  256, 256, 1);
    else if (i < 537728) { int e=i-536576; o_dwk[e] = f2b(dwk[(e&127)*9 + (e>>7)]); }
    else if (i < 540032) { int e=i-537728; o_dwf[e] = f2b(dwf[(e&255)*9 + (e>>8)]); }
    else if (i < 540040) { o_dwf[i-537728] = 0; }   // 16B zero page for OOB halo
}

// ---------------- MFMA conv: blocked A via global_load_lds dbuf, B from L2, BN=64 ----------------
// 1-D swizzled grid: xcd = bid&7 gets contiguous (z,x,y) chunk, y (co-group) innermost.
template<int C0,int C1,int COUT,int KS,int OUTM,int LNF>
__global__ __launch_bounds__(256,4) void mconv_k(
    const unsigned short* __restrict__ in0, int s0,
    const unsigned short* __restrict__ in1, int s1,
    const unsigned short* __restrict__ wp, long wpbs,
    void* __restrict__ outp, int so,
    const unsigned short* __restrict__ in0B,
    const unsigned short* __restrict__ wpB2,
    void* __restrict__ outB,
    const unsigned short* __restrict__ zbuf,
    const float* __restrict__ lnw0, const float* __restrict__ lnb0,
    const float* __restrict__ lnw1, const float* __restrict__ lnb1,
    int ny, int nz)
{
    constexpr int CINT = C0+C1;
    constexpr int KB  = CINT/32;
    constexpr int MT  = 4;
    constexpr int NT  = 2;
    constexpr int RWS = (KS==3)?4:1;
    constexpr int PXS = (KS==3)?66:128;
    constexpr int NTR = RWS*PXS*4;
    constexpr int NLD = (NTR+255)/256;
    constexpr int ASZ = RWS*PXS*32;
    constexpr int EP  = (OUTM==1) ? 64*132*2 : 128*64;
    constexpr int SSZ = (2*ASZ > EP) ? 2*ASZ : EP;
    __shared__ alignas(16) unsigned short sbuf[SSZ];

    const int t = threadIdx.x;
    // swizzled decode
    const int nper = (128*ny*nz) >> 3;
    int lin = (blockIdx.x & 7)*nper + (blockIdx.x >> 3);
    const int gy_ = lin % ny;
    int rem = lin / ny;
    const int gx_ = rem & 127;
    const int gz_ = rem >> 7;
    const int sel = gz_ >> 3;
    const int b   = gz_ & 7;
    const int cob = gy_*64;

    const unsigned short* pin0 = sel ? in0B : in0;
    const unsigned short* wpb  = (sel ? wpB2 : wp) + (size_t)b*wpbs;

    int y0=0,x0=0; size_t p0=0;
    if (KS==3){ y0=(gx_>>1)*2; x0=(gx_&1)*64; }
    else p0 = (size_t)gx_*128;

    const int l = t&63, w = t>>6;
    const int wy = w>>1, wx = w&1;
    const int lrow = l&15, lk = l>>4;

    const size_t b0base = (size_t)b*HW_*s0;
    const size_t b1base = (size_t)b*HW_*s1;

    auto issueA = [&](int kb, int bsel){
        const int cg = kb*32;
        unsigned short* dst = sbuf + bsel*ASZ;
        #pragma unroll
        for (int j=0;j<NLD;++j){
            int i = t + j*256;
            if ((NTR%256)==0 || j<NLD-1 || i<NTR){
                int slot = i&3, pr = i>>2;
                int px = pr%PXS, row = pr/PXS;
                int g = slot ^ (px&3);
                int c = cg + g*8;
                const unsigned short* sp;
                if (KS==3){
                    int gy = y0+row-1, gx = x0+px-1;
                    bool ok = ((unsigned)gy<(unsigned)H_) & ((unsigned)gx<(unsigned)W_);
                    size_t p = (size_t)gy*W_+gx;
                    const unsigned short* base = (c<C0)
                        ? pin0 + b0base + ((size_t)(c>>5)*HW_ + p)*32 + (c&31)
                        : in1  + b1base + ((size_t)((c-C0)>>5)*HW_ + p)*32 + ((c-C0)&31);
                    sp = ok ? base : zbuf;
                } else {
                    size_t p = p0+px;
                    sp = (c<C0)
                        ? pin0 + b0base + ((size_t)(c>>5)*HW_ + p)*32 + (c&31)
                        : in1  + b1base + ((size_t)((c-C0)>>5)*HW_ + p)*32 + ((c-C0)&31);
                }
                gl2lds(sp, dst + (size_t)i*8);
            }
        }
    };
    auto loadB = [&](short8* dst, int kb, int tap){
        #pragma unroll
        for (int n=0;n<NT;++n){
            int fi = (tap*(COUT/16) + (cob>>4) + wx*NT + n)*KB + kb;
            dst[n] = *(const short8*)(wpb + (size_t)fi*512 + l*8);
        }
    };

    f32x4 acc[MT][NT] = {};

    if (KS==3){
        short8 bfs[3][NT];
        issueA(0,0);
        loadB(bfs[0],0,0); loadB(bfs[1],0,1); loadB(bfs[2],0,2);
        for (int kb=0; kb<KB; ++kb){
            __syncthreads();
            unsigned short* cur = sbuf + (kb&1)*ASZ;
            #pragma unroll
            for (int tap=0;tap<9;++tap){
                const int ky=tap/3, kx=tap%3;
                if (tap==2 && kb+1<KB) issueA(kb+1,(kb+1)&1);
                short8 af[MT];
                #pragma unroll
                for (int m=0;m<MT;++m){
                    int pl = wy*64 + m*16 + lrow;
                    int r = (pl>>6)+ky, xx = (pl&63)+kx;
                    af[m] = *(const short8*)&cur[((r*PXS+xx)*4 + (lk^(xx&3)))*8];
                }
                #pragma unroll
                for (int m=0;m<MT;++m)
                    #pragma unroll
                    for (int n=0;n<NT;++n)
                        acc[m][n] = __builtin_amdgcn_mfma_f32_16x16x32_bf16(af[m],bfs[tap%3][n],acc[m][n],0,0,0);
                if (tap+3 < 9)      loadB(bfs[tap%3], kb, tap+3);
                else if (kb+1<KB)   loadB(bfs[tap%3], kb+1, tap-6);
            }
        }
    } else {
        short8 bfs[2][NT];
        issueA(0,0);
        loadB(bfs[0],0,0); if (KB>1) loadB(bfs[1],1,0);
        auto step1 = [&](int kb, short8 (&bcur)[NT]){
            __syncthreads();
            unsigned short* cur = sbuf + (kb&1)*ASZ;
            if (kb+1<KB) issueA(kb+1,(kb+1)&1);
            short8 af[MT];
            #pragma unroll
            for (int m=0;m<MT;++m){
                int pl = wy*64 + m*16 + lrow;
                af[m] = *(const short8*)&cur[(pl*4 + (lk^(pl&3)))*8];
            }
            #pragma unroll
            for (int m=0;m<MT;++m)
                #pragma unroll
                for (int n=0;n<NT;++n)
                    acc[m][n] = __builtin_amdgcn_mfma_f32_16x16x32_bf16(af[m],bcur[n],acc[m][n],0,0,0);
            if (kb+2<KB) loadB(bcur, kb+2, 0);
        };
        for (int kb2=0; kb2<KB; kb2+=2){
            step1(kb2,   bfs[0]);
            step1(kb2+1, bfs[1]);
        }
    }
    __syncthreads();

    if (OUTM==1){
        float* sf = (float*)sbuf;
        #pragma unroll
        for (int m=0;m<MT;++m)
            #pragma unroll
            for (int n=0;n<NT;++n){
                int co_l = wx*32 + n*16 + lrow;
                int pl0  = wy*64 + m*16 + lk*4;
                *(f32x4*)&sf[co_l*132 + pl0] = acc[m][n];
            }
        __syncthreads();
        float* out = (float*)(sel ? outB : outp);
        for (int i=t; i<2048; i+=256){
            int co = i>>5, pxg = i&31;
            f32x4 v = *(const f32x4*)&sf[co*132 + pxg*4];
            *(f32x4*)(out + ((size_t)(b*COUT + cob + co))*HW_ + p0 + pxg*4) = v;
        }
    } else if (LNF){
        #pragma unroll
        for (int m=0;m<MT;++m)
            #pragma unroll
            for (int n=0;n<NT;++n){
                int co = wx*32 + n*16 + lrow;
                int grp = co>>3, cr = co&7;
                #pragma unroll
                for (int r=0;r<4;++r){
                    int pl = wy*64 + m*16 + lk*4 + r;
                    sbuf[pl*64 + ((grp^(pl&7))<<3) + cr] = f2b(acc[m][n][r]);
                }
            }
        __syncthreads();
        if (t < 128){
            int pl = t;
            uint4 raw[8];
            float s = 0.f, ss = 0.f;
            #pragma unroll
            for (int j=0;j<8;++j){
                raw[j] = *(const uint4*)&sbuf[pl*64 + ((j^(pl&7))<<3)];
                float f[8]; up8(raw[j], f);
                #pragma unroll
                for (int k=0;k<8;++k){ s += f[k]; ss += f[k]*f[k]; }
            }
            float mu = s*(1.f/64.f);
            float rs = rsqrtf(ss*(1.f/64.f) - mu*mu + 1e-5f);
            const float* lw = sel ? lnw1 : lnw0;
            const float* lb = sel ? lnb1 : lnb0;
            unsigned short* out = (unsigned short*)(sel ? outB : outp);
            size_t p = (size_t)(y0+(pl>>6))*W_ + x0 + (pl&63);
            #pragma unroll
            for (int j=0;j<8;++j){
                float f[8], o[8];
                up8(raw[j], f);
                #pragma unroll
                for (int k=0;k<8;++k) o[k] = (f[k]-mu)*rs*lw[j*8+k] + lb[j*8+k];
                int cc = j*8;
                unsigned short* dst = out + ((size_t)b*2 + (cc>>5))*(size_t)HW_*32 + p*32 + (cc&31);
                *(uint4*)dst = pk8(o);
            }
        }
    } else {
        unsigned short* out = (unsigned short*)(sel ? outB : outp);
        #pragma unroll
        for (int m=0;m<MT;++m)
            #pragma unroll
            for (int n=0;n<NT;++n){
                int co = wx*32 + n*16 + lrow;
                #pragma unroll
                for (int r=0;r<4;++r){
                    int pl = wy*64 + m*16 + lk*4 + r;
                    sbuf[pl*64 + co] = f2b(acc[m][n][r]);
                }
            }
        __syncthreads();
        for (int i=t; i<1024; i+=256){
            int pl = i>>3, c8 = (i&7)*8;
            size_t p = (KS==3) ? ((size_t)(y0+(pl>>6))*W_ + (size_t)(x0+(pl&63))) : (p0+pl);
            int cc = cob + c8;
            unsigned short* dst = out + (size_t)b*HW_*so + ((size_t)(cc>>5)*HW_ + p)*32 + (cc&31);
            *(uint4*)dst = *(uint4*)&sbuf[pl*64 + c8];
        }
    }
}

// ---------------- channel LayerNorm (blocked bf16, coalesced, shfl group) ----------------
template<int C>
__global__ __launch_bounds__(256) void cln_k(unsigned short* __restrict__ io,
                                             const float* __restrict__ wg,
                                             const float* __restrict__ bi)
{
    constexpr int L = C/8;
    size_t idx = (size_t)blockIdx.x*256 + threadIdx.x;
    int sub = (int)(idx % L);
    size_t pix = idx / L;
    int b = (int)(pix >> 14);
    size_t p = pix & (HW_-1);
    unsigned short* rp = io + ((size_t)b*(C/32) + (sub>>2))*(size_t)HW_*32 + p*32 + (sub&3)*8;
    uint4 raw = *(const uint4*)rp;
    float f[8]; up8(raw, f);
    float s = 0.f, ss = 0.f;
    #pragma unroll
    for (int j=0;j<8;++j){ s += f[j]; ss += f[j]*f[j]; }
    #pragma unroll
    for (int m=1;m<L;m<<=1){ s += __shfl_xor(s,m); ss += __shfl_xor(ss,m); }
    float mu = s*(1.f/C);
    float rs = rsqrtf(ss*(1.f/C) - mu*mu + 1e-5f);
    float4 w0 = *(const float4*)(wg+sub*8), w1 = *(const float4*)(wg+sub*8+4);
    float4 b0 = *(const float4*)(bi+sub*8), b1 = *(const float4*)(bi+sub*8+4);
    float o[8];
    o[0]=(f[0]-mu)*rs*w0.x+b0.x; o[1]=(f[1]-mu)*rs*w0.y+b0.y;
    o[2]=(f[2]-mu)*rs*w0.z+b0.z; o[3]=(f[3]-mu)*rs*w0.w+b0.w;
    o[4]=(f[4]-mu)*rs*w1.x+b1.x; o[5]=(f[5]-mu)*rs*w1.y+b1.y;
    o[6]=(f[6]-mu)*rs*w1.z+b1.z; o[7]=(f[7]-mu)*rs*w1.w+b1.w;
    *(uint4*)rp = pk8(o);
}

// ---------------- depthwise 3x3 blocked bf16 (+GELU) ----------------
template<int CH, bool GELU>
__global__ __launch_bounds__(256) void dw_k(const unsigned short* __restrict__ in,
                                            const unsigned short* __restrict__ wp,
                                            unsigned short* __restrict__ out)
{
    size_t idx = (size_t)blockIdx.x*256 + threadIdx.x;
    int c8 = (int)(idx % (CH/8));
    size_t pix = idx / (CH/8);
    int p = (int)(pix % HW_);
    int b = (int)(pix / HW_);
    int yy = p >> 7, xx = p & 127;
    const unsigned short* ib = in + ((size_t)b*(CH/32) + (c8>>2))*(size_t)HW_*32 + (c8&3)*8;
    float wf[9][8];
    #pragma unroll
    for (int tap=0; tap<9; ++tap){
        uint4 r = *(const uint4*)(wp + tap*CH + c8*8);
        up8(r, wf[tap]);
    }
    float a[8] = {0,0,0,0,0,0,0,0};
    #pragma unroll
    for (int ky=0; ky<3; ++ky){
        int gy = yy+ky-1;
        if ((unsigned)gy >= (unsigned)H_) continue;
        #pragma unroll
        for (int kx=0; kx<3; ++kx){
            int gx = xx+kx-1;
            if ((unsigned)gx >= (unsigned)W_) continue;
            uint4 r = *(const uint4*)(ib + (size_t)(gy*W_+gx)*32);
            float f[8]; up8(r, f);
            #pragma unroll
            for (int j=0;j<8;++j) a[j] += f[j]*wf[ky*3+kx][j];
        }
    }
    if (GELU){
        #pragma unroll
        for (int j=0;j<8;++j) a[j] = 0.5f*a[j]*(1.f + erff(a[j]*0.70710678118654752f));
    }
    unsigned short* ob = out + ((size_t)b*(CH/32) + (c8>>2))*(size_t)HW_*32 + (size_t)p*32 + (c8&3)*8;
    *(uint4*)ob = pk8(a);
}

// ---------------- attention probs per (b,h) ----------------
__global__ __launch_bounds__(256) void attn_k(const unsigned short* __restrict__ qc,
                                              const unsigned short* __restrict__ kvd,
                                              const float* __restrict__ temp,
                                              float* __restrict__ probs)
{
    int b = blockIdx.x >> 3, h = blockIdx.x & 7;
    int t = threadIdx.x;
    const unsigned short* qb = qc  + ((size_t)b*2 + (h>>2))*(size_t)HW_*32 + (h&3)*8;
    const unsigned short* kb = kvd + ((size_t)b*4 + (h>>2))*(size_t)HW_*32 + (h&3)*8;
    float qs[8] = {}, ks[8] = {}, dt[8][8] = {{}};
    for (int p = t; p < HW_; p += 256){
        float qv[8], kv[8];
        up8(*(const uint4*)(qb + (size_t)p*32), qv);
        up8(*(const uint4*)(kb + (size_t)p*32), kv);
        #pragma unroll
        for (int i=0;i<8;++i){ qs[i]+=qv[i]*qv[i]; ks[i]+=kv[i]*kv[i]; }
        #pragma unroll
        for (int i=0;i<8;++i)
            #pragma unroll
            for (int j=0;j<8;++j) dt[i][j] += qv[i]*kv[j];
    }
    __shared__ float red[4][80];
    __shared__ float fin[80];
    int lane = t & 63, wv = t >> 6;
    #pragma unroll
    for (int i=0;i<8;++i){ float v=qs[i]; for (int m=1;m<64;m<<=1) v += __shfl_xor(v,m); if(!lane) red[wv][i]=v; }
    #pragma unroll
    for (int i=0;i<8;++i){ float v=ks[i]; for (int m=1;m<64;m<<=1) v += __shfl_xor(v,m); if(!lane) red[wv][8+i]=v; }
    #pragma unroll
    for (int i=0;i<8;++i)
        #pragma unroll
        for (int j=0;j<8;++j){ float v=dt[i][j]; for (int m=1;m<64;m<<=1) v += __shfl_xor(v,m); if(!lane) red[wv][16+i*8+j]=v; }
    __syncthreads();
    if (t < 80) fin[t] = red[0][t]+red[1][t]+red[2][t]+red[3][t];
    __syncthreads();
    if (t < 8){
        int i = t;
        float qn = fmaxf(sqrtf(fin[i]), 1e-12f);
        float tm = temp[h];
        float lg[8]; float mx = -1e30f;
        #pragma unroll
        for (int j=0;j<8;++j){
            float kn = fmaxf(sqrtf(fin[8+j]), 1e-12f);
            lg[j] = fin[16+i*8+j]/(qn*kn)*tm;
            mx = fmaxf(mx, lg[j]);
        }
        float se = 0.f;
        #pragma unroll
        for (int j=0;j<8;++j){ lg[j]=expf(lg[j]-mx); se+=lg[j]; }
        float inv = 1.f/se;
        #pragma unroll
        for (int j=0;j<8;++j) probs[(((size_t)b*8+h)*8+i)*8+j] = lg[j]*inv;
    }
}

// ---------------- Mb = w_po . blockdiag(attn)  [8][64][64] ----------------
__global__ __launch_bounds__(256) void mb_k(const float* __restrict__ probs,
                                            const float* __restrict__ wpo,
                                            float* __restrict__ Mb)
{
    int b = blockIdx.x;
    for (int o = threadIdx.x; o < 4096; o += 256){
        int co = o >> 6, d = o & 63, h = d >> 3, j = d & 7;
        float s = 0.f;
        #pragma unroll
        for (int i2=0;i2<8;++i2)
            s += wpo[co*64 + h*8 + i2] * probs[(((size_t)b*8+h)*8+i2)*8 + j];
        Mb[(size_t)b*4096 + o] = s;
    }
}

// ---------------- weff: fragment-major per-batch expand weights ----------------
__global__ __launch_bounds__(256) void weff_k(const float* __restrict__ Mb,
                                              const float* __restrict__ wex,
                                              unsigned short* __restrict__ weff)
{
    int b = blockIdx.x / 576;
    int i = (blockIdx.x % 576)*256 + threadIdx.x;
    int tap = i / 16384;
    int rem = i % 16384;
    int coT = rem / 1024;
    int rem2 = rem % 1024;
    int kb = rem2 >> 9;
    int l  = (rem2 >> 3) & 63;
    int ee = rem2 & 7;
    int eo = coT*16 + (l & 15);
    int d  = kb*32 + (l >> 4)*8 + ee;
    const float* mb = Mb + (size_t)b*4096;
    float s = 0.f;
    #pragma unroll 8
    for (int c=0;c<64;++c)
        s += wex[(size_t)(eo*64+c)*9 + tap] * mb[c*64 + d];
    weff[(size_t)b*147456 + i] = f2b(s);
}

extern "C" void kernel_launch(void* const* d_in, const int* in_sizes, int n_in,
                              void* d_out, int out_size, void* d_ws, size_t ws_size,
                              hipStream_t stream) {
    (void)in_sizes; (void)n_in; (void)out_size; (void)ws_size;
    const float* x        = (const float*)d_in[0];
    const float* y        = (const float*)d_in[1];
    const float* w_cq     = (const float*)d_in[2];
    const float* w_ckv    = (const float*)d_in[3];
    const float* ln_q_w   = (const float*)d_in[4];
    const float* ln_q_b   = (const float*)d_in[5];
    const float* ln_kv_w  = (const float*)d_in[6];
    const float* ln_kv_b  = (const float*)d_in[7];
    const float* w_kv     = (const float*)d_in[8];
    const float* w_kvdw   = (const float*)d_in[9];
    const float* w_q      = (const float*)d_in[10];
    const float* temperature = (const float*)d_in[11];
    const float* w_po     = (const float*)d_in[12];
    const float* w_expand = (const float*)d_in[13];
    const float* ln_out_w = (const float*)d_in[14];
    const float* ln_out_b = (const float*)d_in[15];
    const float* w_ffn1   = (const float*)d_in[16];
    const float* w_ffn_dw = (const float*)d_in[17];
    const float* w_ffn2   = (const float*)d_in[18];
    float* outp = (float*)d_out;

    const size_t MB = 1u<<20;
    char* ws8 = (char*)d_ws;
    unsigned short* ykv  = (unsigned short*)(ws8 + 0);        // 16MB
    unsigned short* xq   = (unsigned short*)(ws8 + 16*MB);    // 16MB
    unsigned short* kv1  = (unsigned short*)(ws8 + 32*MB);    // 32MB
    unsigned short* qc   = (unsigned short*)(ws8 + 64*MB);    // 16MB
    unsigned short* kvd  = (unsigned short*)(ws8 + 80*MB);    // 32MB
    unsigned short* vexp = (unsigned short*)(ws8 + 0);        // 64MB
    unsigned short* f2b_ = (unsigned short*)(ws8 + 0);        // 64MB
    float* probs = (float*)(ws8 + 112*MB);
    float* Mb    = (float*)(ws8 + 113*MB);
    unsigned short* weff = (unsigned short*)(ws8 + 114*MB);   // 2.25MB
    unsigned short* wpB  = (unsigned short*)(ws8 + 117*MB);
    unsigned short* wp_cq  = wpB;
    unsigned short* wp_ckv = wpB + 147456;
    unsigned short* wp_q   = wpB + 294912;
    unsigned short* wp_kv  = wpB + 331776;
    unsigned short* wp_f1  = wpB + 339968;
    unsigned short* wp_f2  = wpB + 471040;
    unsigned short* wp_dwk = wpB + 536576;
    unsigned short* wp_dwf = wpB + 537728;
    unsigned short* zbuf   = wpB + 540032;
    unsigned short* xb = (unsigned short*)d_out;              // d_out[0,64MB)
    unsigned short* yb = (unsigned short*)d_out + 32*MB;      // d_out[64,128MB)
    unsigned short* f1 = yb;

    const unsigned short* NUL = (const unsigned short*)nullptr;

    prep_k<<<2111, 256, 0, stream>>>(w_cq, w_ckv, w_q, w_kv, w_ffn1, w_ffn2, w_kvdw, w_ffn_dw,
                                     wp_cq, wp_ckv, wp_q, wp_kv, wp_f1, wp_f2, wp_dwk, wp_dwf);
    pack_k<<<dim3(256,4,16), 256, 0, stream>>>(y, x, yb, xb);
    // fused cq+ckv with in-epilogue LayerNorm
    mconv_k<256,0,64,3,0,1><<<128*1*16, 256, 0, stream>>>(yb,256, NUL,0, wp_ckv,0, ykv,64,
        xb, wp_cq, xq, zbuf, ln_kv_w, ln_kv_b, ln_q_w, ln_q_b, 1, 16);
    mconv_k<64,0,128,1,0,0><<<128*2*8, 256, 0, stream>>>(ykv,64, NUL,0, wp_kv,0, kv1,128,
        ykv, wp_kv, kv1, zbuf, NULL,NULL,NULL,NULL, 2, 8);
    mconv_k<64,0,64,3,0,0><<<128*1*8, 256, 0, stream>>>(xq,64, NUL,0, wp_q,0, qc,64,
        xq, wp_q, qc, zbuf, NULL,NULL,NULL,NULL, 1, 8);
    dw_k<128,false><<<8192, 256, 0, stream>>>(kv1, wp_dwk, kvd);
    attn_k<<<64, 256, 0, stream>>>(qc, kvd, temperature, probs);
    mb_k<<<8, 256, 0, stream>>>(probs, w_po, Mb);
    weff_k<<<4608, 256, 0, stream>>>(Mb, w_expand, weff);
    // fused attn@v + project_out + expand; v = planes 2,3 of kvd (offset HW*64)
    mconv_k<64,0,256,3,0,0><<<128*4*8, 256, 0, stream>>>(kvd + (size_t)HW_*64,128, NUL,0, weff,147456, vexp,256,
        kvd + (size_t)HW_*64, weff, vexp, zbuf, NULL,NULL,NULL,NULL, 4, 8);
    cln_k<256><<<16384, 256, 0, stream>>>(vexp, ln_out_w, ln_out_b);
    mconv_k<256,256,256,1,0,0><<<128*4*8, 256, 0, stream>>>(xb,256, vexp,256, wp_f1,0, f1,256,
        xb, wp_f1, f1, zbuf, NULL,NULL,NULL,NULL, 4, 8);
    dw_k<256,true><<<16384, 256, 0, stream>>>(f1, wp_dwf, f2b_);
    // ffn2: fp32 NCHW output via LDS transpose
    mconv_k<256,0,256,1,1,0><<<128*4*8, 256, 0, stream>>>(f2b_,256, NUL,0, wp_f2,0, outp,0,
        f2b_, wp_f2, outp, zbuf, NULL,NULL,NULL,NULL, 4, 8);
}

// Round 8
// 519.274 us; speedup vs baseline: 9.8643x; 1.1133x over previous
//
#include <hip/hip_runtime.h>
#include <hip/hip_bf16.h>
#include <math.h>

#define B_ 8
#define C_ 256
#define S_ 64
#define H_ 128
#define W_ 128
#define HW_ (H_*W_)
#define P_ (B_*HW_)

typedef __attribute__((ext_vector_type(8))) short short8;
typedef __attribute__((ext_vector_type(4))) float f32x4;

__device__ __forceinline__ unsigned short f2b(float f){
    __hip_bfloat16 h = __float2bfloat16(f);
    return *reinterpret_cast<unsigned short*>(&h);
}
__device__ __forceinline__ void up8(uint4 u, float* f){
    unsigned v0=u.x,v1=u.y,v2=u.z,v3=u.w;
    f[0]=__uint_as_float(v0<<16); f[1]=__uint_as_float(v0&0xffff0000u);
    f[2]=__uint_as_float(v1<<16); f[3]=__uint_as_float(v1&0xffff0000u);
    f[4]=__uint_as_float(v2<<16); f[5]=__uint_as_float(v2&0xffff0000u);
    f[6]=__uint_as_float(v3<<16); f[7]=__uint_as_float(v3&0xffff0000u);
}
__device__ __forceinline__ uint4 pk8(const float* f){
    uint4 u;
    u.x = (unsigned)f2b(f[0]) | ((unsigned)f2b(f[1])<<16);
    u.y = (unsigned)f2b(f[2]) | ((unsigned)f2b(f[3])<<16);
    u.z = (unsigned)f2b(f[4]) | ((unsigned)f2b(f[5])<<16);
    u.w = (unsigned)f2b(f[6]) | ((unsigned)f2b(f[7])<<16);
    return u;
}
__device__ __forceinline__ void gl2lds(const unsigned short* g, unsigned short* l){
    __builtin_amdgcn_global_load_lds((const __attribute__((address_space(1))) void*)g,
                                     (__attribute__((address_space(3))) void*)l, 16, 0, 0);
}

// All activations use C32-blocked layout: [b][C/32][HW][32] (bf16).
// addr(b,c,p) = b*C*HW + (c>>5)*HW*32 + p*32 + (c&31)

// ---------------- NCHW fp32 -> blocked bf16 pack (fused x+y via z) ----------------
__global__ __launch_bounds__(256) void pack_k(const float* __restrict__ inA,
                                              const float* __restrict__ inB,
                                              unsigned short* __restrict__ outA,
                                              unsigned short* __restrict__ outB)
{
    __shared__ unsigned short tl[64][72];
    const int t = threadIdx.x;
    const int p0 = blockIdx.x*64, c0 = blockIdx.y*64;
    const int sel = blockIdx.z >> 3, b = blockIdx.z & 7;
    const float* in = sel ? inB : inA;
    unsigned short* out = sel ? outB : outA;
    const float* ib = in + ((size_t)b*C_ + c0)*HW_ + p0;
    for (int i = t; i < 1024; i += 256){
        int ci = i >> 4, px = (i & 15)*4;
        float4 v = *(const float4*)(ib + (size_t)ci*HW_ + px);
        tl[px+0][ci]=f2b(v.x); tl[px+1][ci]=f2b(v.y); tl[px+2][ci]=f2b(v.z); tl[px+3][ci]=f2b(v.w);
    }
    __syncthreads();
    for (int i = t; i < 512; i += 256){
        int px = i >> 3, c8 = (i & 7)*8;
        int cc = c0 + c8;
        unsigned short* dst = out + ((size_t)b*8 + (cc>>5))*(size_t)HW_*32
                                  + (size_t)(p0+px)*32 + (cc&31);
        *(uint4*)dst = *(uint4*)&tl[px][c8];
    }
}

// ---------------- weight prepack: fragment-major [tap][coT][kb][lane][8] ----------------
__device__ __forceinline__ void packw(const float* __restrict__ src, unsigned short* __restrict__ dst,
                                      int e, int CO, int CI, int KS2)
{
    int KB = CI/32;
    int tap = e / (CO*CI);
    int rem = e % (CO*CI);
    int coT = rem / (CI*16);
    int rem2 = rem % (CI*16);
    int kb = rem2 >> 9;
    int l  = (rem2 >> 3) & 63;
    int ee = rem2 & 7;
    int co = coT*16 + (l & 15);
    int ci = kb*32 + (l >> 4)*8 + ee;
    float v = (KS2==9) ? src[(size_t)(co*CI+ci)*9 + tap] : src[(size_t)co*CI + ci];
    dst[e] = f2b(v);
}

__global__ __launch_bounds__(256) void prep_k(const float* __restrict__ cq, const float* __restrict__ ckv,
                                              const float* __restrict__ q,  const float* __restrict__ kv,
                                              const float* __restrict__ f1, const float* __restrict__ f2,
                                              const float* __restrict__ dwk, const float* __restrict__ dwf,
                                              unsigned short* o_cq, unsigned short* o_ckv, unsigned short* o_q,
                                              unsigned short* o_kv, unsigned short* o_f1, unsigned short* o_f2,
                                              unsigned short* o_dwk, unsigned short* o_dwf)
{
    int i = blockIdx.x*256 + threadIdx.x;
    if      (i < 147456) packw(cq,  o_cq,  i,          64, 256, 9);
    else if (i < 294912) packw(ckv, o_ckv, i-147456,   64, 256, 9);
    else if (i < 331776) packw(q,   o_q,   i-294912,   64,  64, 9);
    else if (i < 339968) packw(kv,  o_kv,  i-331776,  128,  64, 1);
    else if (i < 471040) packw(f1,  o_f1,  i-339968,  256, 512, 1);
    else if (i < 536576) packw(f2,  o_f2,  i-471040,  256, 256, 1);
    else if (i < 537728) { int e=i-536576; o_dwk[e] = f2b(dwk[(e&127)*9 + (e>>7)]); }
    else if (i < 540032) { int e=i-537728; o_dwf[e] = f2b(dwf[(e&255)*9 + (e>>8)]); }
    else if (i < 540040) { o_dwf[i-537728] = 0; }   // 16B zero page for OOB halo
}

// ---------------- MFMA conv: blocked A via global_load_lds dbuf, B from L2, BN=64 ----------------
// 1-D swizzled grid: xcd = bid&7 gets contiguous (z,x,y) chunk, y (co-group) innermost.
// KS=3: A dbuf per 32-ci kb, prefetch issued at top of kb (full 9-tap cover).
// KS=1: A dbuf per 64-ci stage (2 sub-kbs per barrier).
template<int C0,int C1,int COUT,int KS,int OUTM,int LNF>
__global__ __launch_bounds__(256,4) void mconv_k(
    const unsigned short* __restrict__ in0, int s0,
    const unsigned short* __restrict__ in1, int s1,
    const unsigned short* __restrict__ wp, long wpbs,
    void* __restrict__ outp, int so,
    const unsigned short* __restrict__ in0B,
    const unsigned short* __restrict__ wpB2,
    void* __restrict__ outB,
    const unsigned short* __restrict__ zbuf,
    const float* __restrict__ lnw0, const float* __restrict__ lnb0,
    const float* __restrict__ lnw1, const float* __restrict__ lnb1,
    int ny, int nz)
{
    constexpr int CINT = C0+C1;
    constexpr int KB  = CINT/32;
    constexpr int MT  = 4;
    constexpr int NT  = 2;
    constexpr int PXS = (KS==3)?66:128;
    constexpr int ASZ = (KS==3)? 4*66*32 : 8192;     // shorts per buffer (KS1: 64ci stage)
    constexpr int EP  = (OUTM==1) ? 64*132*2 : 128*64;
    constexpr int SSZ = (2*ASZ > EP) ? 2*ASZ : EP;
    __shared__ alignas(16) unsigned short sbuf[SSZ];

    const int t = threadIdx.x;
    // swizzled decode
    const int nper = (128*ny*nz) >> 3;
    int lin = (blockIdx.x & 7)*nper + (blockIdx.x >> 3);
    const int gy_ = lin % ny;
    int rem = lin / ny;
    const int gx_ = rem & 127;
    const int gz_ = rem >> 7;
    const int sel = gz_ >> 3;
    const int b   = gz_ & 7;
    const int cob = gy_*64;

    const unsigned short* pin0 = sel ? in0B : in0;
    const unsigned short* wpb  = (sel ? wpB2 : wp) + (size_t)b*wpbs;

    int y0=0,x0=0; size_t p0=0;
    if (KS==3){ y0=(gx_>>1)*2; x0=(gx_&1)*64; }
    else p0 = (size_t)gx_*128;

    const int l = t&63, w = t>>6;
    const int wy = w>>1, wx = w&1;
    const int lrow = l&15, lk = l>>4;

    const size_t b0base = (size_t)b*HW_*s0;
    const size_t b1base = (size_t)b*HW_*s1;

    // KS=3: stage one 32-ci kb (4 rows x 66 px), source-swizzled for LDS bank spread
    auto issueA3 = [&](int kb, int bsel){
        const int cg = kb*32;
        unsigned short* dst = sbuf + bsel*ASZ;
        #pragma unroll
        for (int j=0;j<5;++j){
            int i = t + j*256;
            if (j<4 || i<1056){
                int slot = i&3, pr = i>>2;
                int px = pr%66, row = pr/66;
                int g = slot ^ (px&3) ^ ((px>>2)&3);
                int c = cg + g*8;
                int gy = y0+row-1, gx = x0+px-1;
                bool ok = ((unsigned)gy<(unsigned)H_) & ((unsigned)gx<(unsigned)W_);
                size_t p = (size_t)gy*W_+gx;
                const unsigned short* base = (c<C0)
                    ? pin0 + b0base + ((size_t)(c>>5)*HW_ + p)*32 + (c&31)
                    : in1  + b1base + ((size_t)((c-C0)>>5)*HW_ + p)*32 + ((c-C0)&31);
                gl2lds(ok ? base : zbuf, dst + (size_t)i*8);
            }
        }
    };
    // KS=1: stage a 64-ci block (two 32-ci halves) of 128 px
    auto issueA1 = [&](int s, int bsel){
        unsigned short* dst = sbuf + bsel*ASZ;
        #pragma unroll
        for (int h=0;h<2;++h){
            const int cg = (s*2+h)*32;
            #pragma unroll
            for (int j=0;j<2;++j){
                int i = t + j*256;
                int slot = i&3, px = i>>2;
                int g = slot ^ (px&3) ^ ((px>>2)&3);
                int c = cg + g*8;
                size_t p = p0+px;
                const unsigned short* sp = (c<C0)
                    ? pin0 + b0base + ((size_t)(c>>5)*HW_ + p)*32 + (c&31)
                    : in1  + b1base + ((size_t)((c-C0)>>5)*HW_ + p)*32 + ((c-C0)&31);
                gl2lds(sp, dst + (size_t)(h*4096 + i*8));
            }
        }
    };
    auto loadB = [&](short8* dst, int kb, int tap){
        #pragma unroll
        for (int n=0;n<NT;++n){
            int fi = (tap*(COUT/16) + (cob>>4) + wx*NT + n)*KB + kb;
            dst[n] = *(const short8*)(wpb + (size_t)fi*512 + l*8);
        }
    };

    f32x4 acc[MT][NT] = {};

    if (KS==3){
        short8 bfs[3][NT];
        issueA3(0,0);
        loadB(bfs[0],0,0); loadB(bfs[1],0,1); loadB(bfs[2],0,2);
        for (int kb=0; kb<KB; ++kb){
            __syncthreads();
            if (kb+1<KB) issueA3(kb+1,(kb+1)&1);   // full-kb cover
            unsigned short* cur = sbuf + (kb&1)*ASZ;
            #pragma unroll
            for (int tap=0;tap<9;++tap){
                const int ky=tap/3, kx=tap%3;
                short8 af[MT];
                #pragma unroll
                for (int m=0;m<MT;++m){
                    int pl = wy*64 + m*16 + lrow;
                    int r = (pl>>6)+ky, xx = (pl&63)+kx;
                    af[m] = *(const short8*)&cur[((r*PXS+xx)*4 + (lk^(xx&3)^((xx>>2)&3)))*8];
                }
                #pragma unroll
                for (int m=0;m<MT;++m)
                    #pragma unroll
                    for (int n=0;n<NT;++n)
                        acc[m][n] = __builtin_amdgcn_mfma_f32_16x16x32_bf16(af[m],bfs[tap%3][n],acc[m][n],0,0,0);
                if (tap+3 < 9)      loadB(bfs[tap%3], kb, tap+3);
                else if (kb+1<KB)   loadB(bfs[tap%3], kb+1, tap-6);
            }
        }
    } else {
        constexpr int KBS = (KB>=2) ? KB/2 : 1;
        short8 bfs[2][NT];
        issueA1(0,0);
        loadB(bfs[0],0,0); loadB(bfs[1],1,0);
        for (int s=0; s<KBS; ++s){
            __syncthreads();
            if (s+1<KBS) issueA1(s+1,(s+1)&1);
            unsigned short* cur = sbuf + (s&1)*ASZ;
            #pragma unroll
            for (int j=0;j<2;++j){
                short8 af[MT];
                #pragma unroll
                for (int m=0;m<MT;++m){
                    int pl = wy*64 + m*16 + lrow;
                    af[m] = *(const short8*)&cur[j*4096 + (pl*4 + (lk^(pl&3)^((pl>>2)&3)))*8];
                }
                #pragma unroll
                for (int m=0;m<MT;++m)
                    #pragma unroll
                    for (int n=0;n<NT;++n)
                        acc[m][n] = __builtin_amdgcn_mfma_f32_16x16x32_bf16(af[m],bfs[j][n],acc[m][n],0,0,0);
                if (s*2+j+2 < KB) loadB(bfs[j], s*2+j+2, 0);
            }
        }
    }
    __syncthreads();

    if (OUTM==1){
        float* sf = (float*)sbuf;
        #pragma unroll
        for (int m=0;m<MT;++m)
            #pragma unroll
            for (int n=0;n<NT;++n){
                int co_l = wx*32 + n*16 + lrow;
                int pl0  = wy*64 + m*16 + lk*4;
                *(f32x4*)&sf[co_l*132 + pl0] = acc[m][n];
            }
        __syncthreads();
        float* out = (float*)(sel ? outB : outp);
        for (int i=t; i<2048; i+=256){
            int co = i>>5, pxg = i&31;
            f32x4 v = *(const f32x4*)&sf[co*132 + pxg*4];
            *(f32x4*)(out + ((size_t)(b*COUT + cob + co))*HW_ + p0 + pxg*4) = v;
        }
    } else if (LNF){
        #pragma unroll
        for (int m=0;m<MT;++m)
            #pragma unroll
            for (int n=0;n<NT;++n){
                int co = wx*32 + n*16 + lrow;
                int grp = co>>3, cr = co&7;
                #pragma unroll
                for (int r=0;r<4;++r){
                    int pl = wy*64 + m*16 + lk*4 + r;
                    sbuf[pl*64 + ((grp^(pl&7))<<3) + cr] = f2b(acc[m][n][r]);
                }
            }
        __syncthreads();
        if (t < 128){
            int pl = t;
            uint4 raw[8];
            float s = 0.f, ss = 0.f;
            #pragma unroll
            for (int j=0;j<8;++j){
                raw[j] = *(const uint4*)&sbuf[pl*64 + ((j^(pl&7))<<3)];
                float f[8]; up8(raw[j], f);
                #pragma unroll
                for (int k=0;k<8;++k){ s += f[k]; ss += f[k]*f[k]; }
            }
            float mu = s*(1.f/64.f);
            float rs = rsqrtf(ss*(1.f/64.f) - mu*mu + 1e-5f);
            const float* lw = sel ? lnw1 : lnw0;
            const float* lb = sel ? lnb1 : lnb0;
            unsigned short* out = (unsigned short*)(sel ? outB : outp);
            size_t p = (size_t)(y0+(pl>>6))*W_ + x0 + (pl&63);
            #pragma unroll
            for (int j=0;j<8;++j){
                float f[8], o[8];
                up8(raw[j], f);
                #pragma unroll
                for (int k=0;k<8;++k) o[k] = (f[k]-mu)*rs*lw[j*8+k] + lb[j*8+k];
                int cc = j*8;
                unsigned short* dst = out + ((size_t)b*2 + (cc>>5))*(size_t)HW_*32 + p*32 + (cc&31);
                *(uint4*)dst = pk8(o);
            }
        }
    } else {
        unsigned short* out = (unsigned short*)(sel ? outB : outp);
        #pragma unroll
        for (int m=0;m<MT;++m)
            #pragma unroll
            for (int n=0;n<NT;++n){
                int co = wx*32 + n*16 + lrow;
                #pragma unroll
                for (int r=0;r<4;++r){
                    int pl = wy*64 + m*16 + lk*4 + r;
                    sbuf[pl*64 + co] = f2b(acc[m][n][r]);
                }
            }
        __syncthreads();
        for (int i=t; i<1024; i+=256){
            int pl = i>>3, c8 = (i&7)*8;
            size_t p = (KS==3) ? ((size_t)(y0+(pl>>6))*W_ + (size_t)(x0+(pl&63))) : (p0+pl);
            int cc = cob + c8;
            unsigned short* dst = out + (size_t)b*HW_*so + ((size_t)(cc>>5)*HW_ + p)*32 + (cc&31);
            *(uint4*)dst = *(uint4*)&sbuf[pl*64 + c8];
        }
    }
}

// ---------------- channel LayerNorm (blocked bf16, coalesced, shfl group) ----------------
template<int C>
__global__ __launch_bounds__(256) void cln_k(unsigned short* __restrict__ io,
                                             const float* __restrict__ wg,
                                             const float* __restrict__ bi)
{
    constexpr int L = C/8;
    size_t idx = (size_t)blockIdx.x*256 + threadIdx.x;
    int sub = (int)(idx % L);
    size_t pix = idx / L;
    int b = (int)(pix >> 14);
    size_t p = pix & (HW_-1);
    unsigned short* rp = io + ((size_t)b*(C/32) + (sub>>2))*(size_t)HW_*32 + p*32 + (sub&3)*8;
    uint4 raw = *(const uint4*)rp;
    float f[8]; up8(raw, f);
    float s = 0.f, ss = 0.f;
    #pragma unroll
    for (int j=0;j<8;++j){ s += f[j]; ss += f[j]*f[j]; }
    #pragma unroll
    for (int m=1;m<L;m<<=1){ s += __shfl_xor(s,m); ss += __shfl_xor(ss,m); }
    float mu = s*(1.f/C);
    float rs = rsqrtf(ss*(1.f/C) - mu*mu + 1e-5f);
    float4 w0 = *(const float4*)(wg+sub*8), w1 = *(const float4*)(wg+sub*8+4);
    float4 b0 = *(const float4*)(bi+sub*8), b1 = *(const float4*)(bi+sub*8+4);
    float o[8];
    o[0]=(f[0]-mu)*rs*w0.x+b0.x; o[1]=(f[1]-mu)*rs*w0.y+b0.y;
    o[2]=(f[2]-mu)*rs*w0.z+b0.z; o[3]=(f[3]-mu)*rs*w0.w+b0.w;
    o[4]=(f[4]-mu)*rs*w1.x+b1.x; o[5]=(f[5]-mu)*rs*w1.y+b1.y;
    o[6]=(f[6]-mu)*rs*w1.z+b1.z; o[7]=(f[7]-mu)*rs*w1.w+b1.w;
    *(uint4*)rp = pk8(o);
}

// ---------------- depthwise 3x3 blocked bf16 (+GELU) ----------------
template<int CH, bool GELU>
__global__ __launch_bounds__(256) void dw_k(const unsigned short* __restrict__ in,
                                            const unsigned short* __restrict__ wp,
                                            unsigned short* __restrict__ out)
{
    size_t idx = (size_t)blockIdx.x*256 + threadIdx.x;
    int c8 = (int)(idx % (CH/8));
    size_t pix = idx / (CH/8);
    int p = (int)(pix % HW_);
    int b = (int)(pix / HW_);
    int yy = p >> 7, xx = p & 127;
    const unsigned short* ib = in + ((size_t)b*(CH/32) + (c8>>2))*(size_t)HW_*32 + (c8&3)*8;
    float wf[9][8];
    #pragma unroll
    for (int tap=0; tap<9; ++tap){
        uint4 r = *(const uint4*)(wp + tap*CH + c8*8);
        up8(r, wf[tap]);
    }
    float a[8] = {0,0,0,0,0,0,0,0};
    #pragma unroll
    for (int ky=0; ky<3; ++ky){
        int gy = yy+ky-1;
        if ((unsigned)gy >= (unsigned)H_) continue;
        #pragma unroll
        for (int kx=0; kx<3; ++kx){
            int gx = xx+kx-1;
            if ((unsigned)gx >= (unsigned)W_) continue;
            uint4 r = *(const uint4*)(ib + (size_t)(gy*W_+gx)*32);
            float f[8]; up8(r, f);
            #pragma unroll
            for (int j=0;j<8;++j) a[j] += f[j]*wf[ky*3+kx][j];
        }
    }
    if (GELU){
        #pragma unroll
        for (int j=0;j<8;++j) a[j] = 0.5f*a[j]*(1.f + erff(a[j]*0.70710678118654752f));
    }
    unsigned short* ob = out + ((size_t)b*(CH/32) + (c8>>2))*(size_t)HW_*32 + (size_t)p*32 + (c8&3)*8;
    *(uint4*)ob = pk8(a);
}

// ---------------- attention probs per (b,h) ----------------
__global__ __launch_bounds__(256) void attn_k(const unsigned short* __restrict__ qc,
                                              const unsigned short* __restrict__ kvd,
                                              const float* __restrict__ temp,
                                              float* __restrict__ probs)
{
    int b = blockIdx.x >> 3, h = blockIdx.x & 7;
    int t = threadIdx.x;
    const unsigned short* qb = qc  + ((size_t)b*2 + (h>>2))*(size_t)HW_*32 + (h&3)*8;
    const unsigned short* kb = kvd + ((size_t)b*4 + (h>>2))*(size_t)HW_*32 + (h&3)*8;
    float qs[8] = {}, ks[8] = {}, dt[8][8] = {{}};
    for (int p = t; p < HW_; p += 256){
        float qv[8], kv[8];
        up8(*(const uint4*)(qb + (size_t)p*32), qv);
        up8(*(const uint4*)(kb + (size_t)p*32), kv);
        #pragma unroll
        for (int i=0;i<8;++i){ qs[i]+=qv[i]*qv[i]; ks[i]+=kv[i]*kv[i]; }
        #pragma unroll
        for (int i=0;i<8;++i)
            #pragma unroll
            for (int j=0;j<8;++j) dt[i][j] += qv[i]*kv[j];
    }
    __shared__ float red[4][80];
    __shared__ float fin[80];
    int lane = t & 63, wv = t >> 6;
    #pragma unroll
    for (int i=0;i<8;++i){ float v=qs[i]; for (int m=1;m<64;m<<=1) v += __shfl_xor(v,m); if(!lane) red[wv][i]=v; }
    #pragma unroll
    for (int i=0;i<8;++i){ float v=ks[i]; for (int m=1;m<64;m<<=1) v += __shfl_xor(v,m); if(!lane) red[wv][8+i]=v; }
    #pragma unroll
    for (int i=0;i<8;++i)
        #pragma unroll
        for (int j=0;j<8;++j){ float v=dt[i][j]; for (int m=1;m<64;m<<=1) v += __shfl_xor(v,m); if(!lane) red[wv][16+i*8+j]=v; }
    __syncthreads();
    if (t < 80) fin[t] = red[0][t]+red[1][t]+red[2][t]+red[3][t];
    __syncthreads();
    if (t < 8){
        int i = t;
        float qn = fmaxf(sqrtf(fin[i]), 1e-12f);
        float tm = temp[h];
        float lg[8]; float mx = -1e30f;
        #pragma unroll
        for (int j=0;j<8;++j){
            float kn = fmaxf(sqrtf(fin[8+j]), 1e-12f);
            lg[j] = fin[16+i*8+j]/(qn*kn)*tm;
            mx = fmaxf(mx, lg[j]);
        }
        float se = 0.f;
        #pragma unroll
        for (int j=0;j<8;++j){ lg[j]=expf(lg[j]-mx); se+=lg[j]; }
        float inv = 1.f/se;
        #pragma unroll
        for (int j=0;j<8;++j) probs[(((size_t)b*8+h)*8+i)*8+j] = lg[j]*inv;
    }
}

// ---------------- Mb = w_po . blockdiag(attn)  [8][64][64] ----------------
__global__ __launch_bounds__(256) void mb_k(const float* __restrict__ probs,
                                            const float* __restrict__ wpo,
                                            float* __restrict__ Mb)
{
    int b = blockIdx.x;
    for (int o = threadIdx.x; o < 4096; o += 256){
        int co = o >> 6, d = o & 63, h = d >> 3, j = d & 7;
        float s = 0.f;
        #pragma unroll
        for (int i2=0;i2<8;++i2)
            s += wpo[co*64 + h*8 + i2] * probs[(((size_t)b*8+h)*8+i2)*8 + j];
        Mb[(size_t)b*4096 + o] = s;
    }
}

// ---------------- weff: fragment-major per-batch expand weights ----------------
__global__ __launch_bounds__(256) void weff_k(const float* __restrict__ Mb,
                                              const float* __restrict__ wex,
                                              unsigned short* __restrict__ weff)
{
    int b = blockIdx.x / 576;
    int i = (blockIdx.x % 576)*256 + threadIdx.x;
    int tap = i / 16384;
    int rem = i % 16384;
    int coT = rem / 1024;
    int rem2 = rem % 1024;
    int kb = rem2 >> 9;
    int l  = (rem2 >> 3) & 63;
    int ee = rem2 & 7;
    int eo = coT*16 + (l & 15);
    int d  = kb*32 + (l >> 4)*8 + ee;
    const float* mb = Mb + (size_t)b*4096;
    float s = 0.f;
    #pragma unroll 8
    for (int c=0;c<64;++c)
        s += wex[(size_t)(eo*64+c)*9 + tap] * mb[c*64 + d];
    weff[(size_t)b*147456 + i] = f2b(s);
}

extern "C" void kernel_launch(void* const* d_in, const int* in_sizes, int n_in,
                              void* d_out, int out_size, void* d_ws, size_t ws_size,
                              hipStream_t stream) {
    (void)in_sizes; (void)n_in; (void)out_size; (void)ws_size;
    const float* x        = (const float*)d_in[0];
    const float* y        = (const float*)d_in[1];
    const float* w_cq     = (const float*)d_in[2];
    const float* w_ckv    = (const float*)d_in[3];
    const float* ln_q_w   = (const float*)d_in[4];
    const float* ln_q_b   = (const float*)d_in[5];
    const float* ln_kv_w  = (const float*)d_in[6];
    const float* ln_kv_b  = (const float*)d_in[7];
    const float* w_kv     = (const float*)d_in[8];
    const float* w_kvdw   = (const float*)d_in[9];
    const float* w_q      = (const float*)d_in[10];
    const float* temperature = (const float*)d_in[11];
    const float* w_po     = (const float*)d_in[12];
    const float* w_expand = (const float*)d_in[13];
    const float* ln_out_w = (const float*)d_in[14];
    const float* ln_out_b = (const float*)d_in[15];
    const float* w_ffn1   = (const float*)d_in[16];
    const float* w_ffn_dw = (const float*)d_in[17];
    const float* w_ffn2   = (const float*)d_in[18];
    float* outp = (float*)d_out;

    const size_t MB = 1u<<20;
    char* ws8 = (char*)d_ws;
    unsigned short* ykv  = (unsigned short*)(ws8 + 0);        // 16MB
    unsigned short* xq   = (unsigned short*)(ws8 + 16*MB);    // 16MB
    unsigned short* kv1  = (unsigned short*)(ws8 + 32*MB);    // 32MB
    unsigned short* qc   = (unsigned short*)(ws8 + 64*MB);    // 16MB
    unsigned short* kvd  = (unsigned short*)(ws8 + 80*MB);    // 32MB
    unsigned short* vexp = (unsigned short*)(ws8 + 0);        // 64MB
    unsigned short* f2b_ = (unsigned short*)(ws8 + 0);        // 64MB
    float* probs = (float*)(ws8 + 112*MB);
    float* Mb    = (float*)(ws8 + 113*MB);
    unsigned short* weff = (unsigned short*)(ws8 + 114*MB);   // 2.25MB
    unsigned short* wpB  = (unsigned short*)(ws8 + 117*MB);
    unsigned short* wp_cq  = wpB;
    unsigned short* wp_ckv = wpB + 147456;
    unsigned short* wp_q   = wpB + 294912;
    unsigned short* wp_kv  = wpB + 331776;
    unsigned short* wp_f1  = wpB + 339968;
    unsigned short* wp_f2  = wpB + 471040;
    unsigned short* wp_dwk = wpB + 536576;
    unsigned short* wp_dwf = wpB + 537728;
    unsigned short* zbuf   = wpB + 540032;
    unsigned short* xb = (unsigned short*)d_out;              // d_out[0,64MB)
    unsigned short* yb = (unsigned short*)d_out + 32*MB;      // d_out[64,128MB)
    unsigned short* f1 = yb;

    const unsigned short* NUL = (const unsigned short*)nullptr;

    prep_k<<<2111, 256, 0, stream>>>(w_cq, w_ckv, w_q, w_kv, w_ffn1, w_ffn2, w_kvdw, w_ffn_dw,
                                     wp_cq, wp_ckv, wp_q, wp_kv, wp_f1, wp_f2, wp_dwk, wp_dwf);
    pack_k<<<dim3(256,4,16), 256, 0, stream>>>(y, x, yb, xb);
    // fused cq+ckv with in-epilogue LayerNorm
    mconv_k<256,0,64,3,0,1><<<128*1*16, 256, 0, stream>>>(yb,256, NUL,0, wp_ckv,0, ykv,64,
        xb, wp_cq, xq, zbuf, ln_kv_w, ln_kv_b, ln_q_w, ln_q_b, 1, 16);
    mconv_k<64,0,128,1,0,0><<<128*2*8, 256, 0, stream>>>(ykv,64, NUL,0, wp_kv,0, kv1,128,
        ykv, wp_kv, kv1, zbuf, NULL,NULL,NULL,NULL, 2, 8);
    mconv_k<64,0,64,3,0,0><<<128*1*8, 256, 0, stream>>>(xq,64, NUL,0, wp_q,0, qc,64,
        xq, wp_q, qc, zbuf, NULL,NULL,NULL,NULL, 1, 8);
    dw_k<128,false><<<8192, 256, 0, stream>>>(kv1, wp_dwk, kvd);
    attn_k<<<64, 256, 0, stream>>>(qc, kvd, temperature, probs);
    mb_k<<<8, 256, 0, stream>>>(probs, w_po, Mb);
    weff_k<<<4608, 256, 0, stream>>>(Mb, w_expand, weff);
    // fused attn@v + project_out + expand; v = planes 2,3 of kvd (offset HW*64)
    mconv_k<64,0,256,3,0,0><<<128*4*8, 256, 0, stream>>>(kvd + (size_t)HW_*64,128, NUL,0, weff,147456, vexp,256,
        kvd + (size_t)HW_*64, weff, vexp, zbuf, NULL,NULL,NULL,NULL, 4, 8);
    cln_k<256><<<16384, 256, 0, stream>>>(vexp, ln_out_w, ln_out_b);
    mconv_k<256,256,256,1,0,0><<<128*4*8, 256, 0, stream>>>(xb,256, vexp,256, wp_f1,0, f1,256,
        xb, wp_f1, f1, zbuf, NULL,NULL,NULL,NULL, 4, 8);
    dw_k<256,true><<<16384, 256, 0, stream>>>(f1, wp_dwf, f2b_);
    // ffn2: fp32 NCHW output via LDS transpose
    mconv_k<256,0,256,1,1,0><<<128*4*8, 256, 0, stream>>>(f2b_,256, NUL,0, wp_f2,0, outp,0,
        f2b_, wp_f2, outp, zbuf, NULL,NULL,NULL,NULL, 4, 8);
}